// Round 1
// baseline (3779.342 us; speedup 1.0000x reference)
//
#include <hip/hip_runtime.h>

// ---------------- problem constants (match setup_inputs) ----------------
constexpr int Bn = 2, Cn = 3, Hh = 512, Ww = 512;
constexpr int KS = 15, KR = 7;          // PSF kernel
constexpr int NDK = 6, NRK = 5;         // data / reg bank sizes (5x5, r=2)
constexpr int GH = 64, GW = 64, NBn = 9, SS = 8;  // bilateral grid
constexpr float EPSf = 1e-8f;
constexpr float CGTOL = 1e-4f;
constexpr int PLANE = Hh * Ww;          // 262144
constexpr int CHW = Cn * PLANE;         // 786432
constexpr int TIL = 16;
constexpr int TX = Ww / TIL, TY = Hh / TIL;  // 32 x 32 tiles
constexpr int BPB = Cn * TX * TY;       // 3072 blocks per batch (reductions)
constexpr int NITER = 5;                // num_cg_iter from setup (device-guarded vs *ncg)

struct CgState { float alpha, beta, rn, r0; int done, pflag; int pad0, pad1; };

// ---------------------------------------------------------------------
// k_corr15: 15x15 correlation with on-the-fly vector update fused in.
// mode 0: v = src                       (init; optionally copy v -> outPlane)
// mode 1: v = skip ? src : src+alpha*aux  (x-update), write v -> outPlane
// mode 2: v = pflag ? aux+beta*src : src  (p-update), write v -> outPlane
// corrOut = corr(v, kern_b) - (sub ? sub : 0)
// ---------------------------------------------------------------------
__global__ __launch_bounds__(256)
void k_corr15(const float* __restrict__ src, const float* __restrict__ aux,
              float* __restrict__ outPlane, const float* __restrict__ sub,
              float* __restrict__ corrOut, const float* __restrict__ kernB,
              const CgState* __restrict__ st, const int* __restrict__ ncg,
              int iter, int mode)
{
    __shared__ float tile[30 * 30];
    __shared__ float kk[KS * KS];
    const int tx = threadIdx.x, ty = threadIdx.y;
    const int tid = ty * TIL + tx;
    const int pz = blockIdx.z;
    const int b = pz / Cn;
    const int baseP = pz * PLANE;
    const int ox0 = blockIdx.x * TIL, oy0 = blockIdx.y * TIL;

    const CgState s = st[b];
    const int n_cg = *ncg;
    const bool doneSkip = (mode != 0) && ((s.done != 0) || (iter >= n_cg));
    const float alpha = s.alpha, beta = s.beta;
    const int pf = (mode == 2 && s.pflag != 0 && !doneSkip) ? 1 : 0;

    const float* kp = kernB + b * KS * KS;
    for (int i = tid; i < KS * KS; i += 256) kk[i] = kp[i];
    for (int i = tid; i < 30 * 30; i += 256) {
        int ly = i / 30, lx = i % 30;
        int gy = oy0 - KR + ly, gx = ox0 - KR + lx;
        float v = 0.f;
        if (gy >= 0 && gy < Hh && gx >= 0 && gx < Ww) {
            int gi = baseP + gy * Ww + gx;
            float sv = src[gi];
            if (mode == 0)      v = sv;
            else if (mode == 1) v = doneSkip ? sv : sv + alpha * aux[gi];
            else                v = pf ? (aux[gi] + beta * sv) : sv;
        }
        tile[i] = v;
    }
    __syncthreads();
    const int gi = baseP + (oy0 + ty) * Ww + (ox0 + tx);
    if (outPlane) outPlane[gi] = tile[(ty + KR) * 30 + (tx + KR)];
    if (doneSkip) return;
    float acc = 0.f;
    for (int i = 0; i < KS; i++)
        for (int j = 0; j < KS; j++)
            acc = fmaf(kk[i * KS + j], tile[(ty + i) * 30 + (tx + j)], acc);
    corrOut[gi] = sub ? (acc - sub[gi]) : acc;
}

// ---------------------------------------------------------------------
// k_u: fused conv_bank + weighted conv_bank_T over the data kernels.
// u = sum_n 2*dkw[n] * corr( corr(Kx, dk_n) [zero outside image], flip(dk_n) )
// ---------------------------------------------------------------------
__global__ __launch_bounds__(256)
void k_u(const float* __restrict__ kxbuf, float* __restrict__ ubuf,
         const float* __restrict__ dks, const float* __restrict__ dkw,
         const CgState* __restrict__ st, const int* __restrict__ ncg,
         int iter, int mode)
{
    const int b = blockIdx.z / Cn;
    if (mode == 1 && (st[b].done != 0 || iter >= *ncg)) return;
    __shared__ float kx[24 * 24];
    __shared__ float dl[20 * 20];
    __shared__ float dkk[NDK * 25];
    __shared__ float dww[NDK];
    const int tx = threadIdx.x, ty = threadIdx.y, tid = ty * 16 + tx;
    const int baseP = blockIdx.z * PLANE;
    const int ox0 = blockIdx.x * 16, oy0 = blockIdx.y * 16;
    for (int i = tid; i < NDK * 25; i += 256) dkk[i] = dks[i];
    if (tid < NDK) dww[tid] = dkw[tid];
    for (int i = tid; i < 24 * 24; i += 256) {
        int ly = i / 24, lx = i % 24;
        int gy = oy0 - 4 + ly, gx = ox0 - 4 + lx;
        kx[i] = (gy >= 0 && gy < Hh && gx >= 0 && gx < Ww) ? kxbuf[baseP + gy * Ww + gx] : 0.f;
    }
    __syncthreads();
    float u = 0.f;
    for (int n = 0; n < NDK; n++) {
        float w = 2.f * dww[n];
        if (w == 0.f) continue;          // uniform across block
        const float* dn = &dkk[n * 25];
        for (int i = tid; i < 400; i += 256) {
            int zy = i / 20, zx = i % 20;
            int gy = oy0 - 2 + zy, gx = ox0 - 2 + zx;
            float d = 0.f;
            if (gy >= 0 && gy < Hh && gx >= 0 && gx < Ww) {
                for (int a = 0; a < 5; a++)
                    for (int bb = 0; bb < 5; bb++)
                        d = fmaf(dn[a * 5 + bb], kx[(zy + a) * 24 + (zx + bb)], d);
            }
            dl[i] = d;
        }
        __syncthreads();
        float acc = 0.f;
        for (int a = 0; a < 5; a++)
            for (int bb = 0; bb < 5; bb++)
                acc = fmaf(dn[(4 - a) * 5 + (4 - bb)], dl[(ty + a) * 20 + (tx + bb)], acc);
        u = fmaf(w, acc, u);
        __syncthreads();
    }
    ubuf[baseP + (oy0 + ty) * Ww + (ox0 + tx)] = u;
}

// ---------------------------------------------------------------------
// k_D: g = conv2d_T(u, kern) + sum_m corr( wphi_m [zero outside], flip(rk_m) )
//   wphi_m(z) = rkw_m*rp_m*sign(v)*(|v|+EPS)^(rp_m-1),  v = corr(x,rk_m)(z)-tgt_m(z)
// writes r = -g (and p on init), reduces ||g||^2 into partials slot 0.
// ---------------------------------------------------------------------
__global__ __launch_bounds__(256)
void k_D(const float* __restrict__ ubuf, const float* __restrict__ xnew,
         const float* __restrict__ tgt, float* __restrict__ rbuf,
         float* __restrict__ pout, const float* __restrict__ kernB,
         const float* __restrict__ rks, const float* __restrict__ rkw,
         const float* __restrict__ rpw, float* __restrict__ part,
         const CgState* __restrict__ st, const int* __restrict__ ncg,
         int iter, int mode)
{
    const int pz = blockIdx.z, b = pz / Cn, c = pz % Cn;
    if (mode == 1 && (st[b].done != 0 || iter >= *ncg)) return;
    __shared__ float ul[30 * 30];
    __shared__ float xl[24 * 24];
    __shared__ float wl[20 * 20];
    __shared__ float kk[KS * KS];
    __shared__ float rkk[NRK * 25];
    __shared__ float srkw[NRK], srpw[NRK];
    __shared__ float red[256];
    const int tx = threadIdx.x, ty = threadIdx.y, tid = ty * 16 + tx;
    const int ox0 = blockIdx.x * 16, oy0 = blockIdx.y * 16;
    const int baseP = pz * PLANE;
    const float* kp = kernB + b * KS * KS;
    for (int i = tid; i < KS * KS; i += 256) kk[i] = kp[i];
    for (int i = tid; i < NRK * 25; i += 256) rkk[i] = rks[i];
    if (tid < NRK) { srkw[tid] = rkw[tid]; srpw[tid] = rpw[tid]; }
    for (int i = tid; i < 30 * 30; i += 256) {
        int ly = i / 30, lx = i % 30;
        int gy = oy0 - KR + ly, gx = ox0 - KR + lx;
        ul[i] = (gy >= 0 && gy < Hh && gx >= 0 && gx < Ww) ? ubuf[baseP + gy * Ww + gx] : 0.f;
    }
    for (int i = tid; i < 24 * 24; i += 256) {
        int ly = i / 24, lx = i % 24;
        int gy = oy0 - 4 + ly, gx = ox0 - 4 + lx;
        xl[i] = (gy >= 0 && gy < Hh && gx >= 0 && gx < Ww) ? xnew[baseP + gy * Ww + gx] : 0.f;
    }
    __syncthreads();
    float g = 0.f;
    for (int i = 0; i < KS; i++)
        for (int j = 0; j < KS; j++)
            g = fmaf(kk[(KS - 1 - i) * KS + (KS - 1 - j)], ul[(ty + i) * 30 + (tx + j)], g);
    for (int m = 0; m < NRK; m++) {
        float wm = srkw[m];
        if (wm == 0.f) continue;         // uniform
        float rp = srpw[m];
        const float* rm = &rkk[m * 25];
        const float* tgm = tgt ? tgt + ((size_t)(b * NRK + m)) * CHW + (size_t)c * PLANE : nullptr;
        for (int i = tid; i < 400; i += 256) {
            int zy = i / 20, zx = i % 20;
            int gy = oy0 - 2 + zy, gx = ox0 - 2 + zx;
            float ww = 0.f;
            if (gy >= 0 && gy < Hh && gx >= 0 && gx < Ww) {
                float v = 0.f;
                for (int a = 0; a < 5; a++)
                    for (int bb = 0; bb < 5; bb++)
                        v = fmaf(rm[a * 5 + bb], xl[(zy + a) * 24 + (zx + bb)], v);
                if (tgm) v -= tgm[gy * Ww + gx];
                float sg = (v > 0.f) ? 1.f : ((v < 0.f) ? -1.f : 0.f);
                float av = fabsf(v) + EPSf;
                float pw = (rp == 2.f) ? av : powf(av, rp - 1.f);
                ww = wm * rp * sg * pw;
            }
            wl[i] = ww;
        }
        __syncthreads();
        for (int a = 0; a < 5; a++)
            for (int bb = 0; bb < 5; bb++)
                g = fmaf(rm[(4 - a) * 5 + (4 - bb)], wl[(ty + a) * 20 + (tx + bb)], g);
        __syncthreads();
    }
    const int gi = baseP + (oy0 + ty) * Ww + (ox0 + tx);
    float r = -g;
    rbuf[gi] = r;
    if (pout) pout[gi] = r;
    red[tid] = g * g;
    __syncthreads();
    for (int s2 = 128; s2 > 0; s2 >>= 1) { if (tid < s2) red[tid] += red[tid + s2]; __syncthreads(); }
    if (tid == 0) {
        int blk = c * (TX * TY) + blockIdx.y * TX + blockIdx.x;
        part[((size_t)b * 4 + 0) * BPB + blk] = red[0];
    }
}

// ---------------------------------------------------------------------
// k_alpha: per-pixel num = r*p ; den1 = sum_n 2*dkw_n*corr(Kp,dk_n)^2 ;
// den2 = sum_m rkw*rp*(rp-1)*(|v|+EPS)^(rp-2)*corr(p,rk_m)^2. Block partials.
// ---------------------------------------------------------------------
__global__ __launch_bounds__(256)
void k_alpha(const float* __restrict__ kpbuf, const float* __restrict__ pnew,
             const float* __restrict__ rbuf, const float* __restrict__ xcur,
             const float* __restrict__ tgt,
             const float* __restrict__ dks, const float* __restrict__ dkw,
             const float* __restrict__ rks, const float* __restrict__ rkw,
             const float* __restrict__ rpw,
             float* __restrict__ part, const CgState* __restrict__ st,
             const int* __restrict__ ncg, int iter)
{
    const int pz = blockIdx.z, b = pz / Cn, c = pz % Cn;
    if (st[b].done != 0 || iter >= *ncg) return;
    __shared__ float kl[24 * 24], pl[24 * 24], xl[24 * 24];
    __shared__ float dkk[NDK * 25], rkk[NRK * 25];
    __shared__ float sdkw[NDK], srkw[NRK], srpw[NRK];
    __shared__ float red[256];
    const int tx = threadIdx.x, ty = threadIdx.y, tid = ty * 16 + tx;
    const int ox0 = blockIdx.x * 16, oy0 = blockIdx.y * 16;
    const int baseP = pz * PLANE;
    for (int i = tid; i < NDK * 25; i += 256) dkk[i] = dks[i];
    for (int i = tid; i < NRK * 25; i += 256) rkk[i] = rks[i];
    if (tid < NDK) sdkw[tid] = dkw[tid];
    if (tid < NRK) { srkw[tid] = rkw[tid]; srpw[tid] = rpw[tid]; }
    for (int i = tid; i < 24 * 24; i += 256) {
        int ly = i / 24, lx = i % 24;
        int gy = oy0 - 2 + ly, gx = ox0 - 2 + lx;
        bool in = gy >= 0 && gy < Hh && gx >= 0 && gx < Ww;
        int gidx = baseP + gy * Ww + gx;
        kl[i] = in ? kpbuf[gidx] : 0.f;
        pl[i] = in ? pnew[gidx] : 0.f;
    }
    __syncthreads();
    bool need_v = false;
    for (int m = 0; m < NRK; m++) {
        float rp = srpw[m];
        if (srkw[m] * rp * (rp - 1.f) != 0.f && rp != 2.f) need_v = true;
    }
    if (need_v) {
        for (int i = tid; i < 24 * 24; i += 256) {
            int ly = i / 24, lx = i % 24;
            int gy = oy0 - 2 + ly, gx = ox0 - 2 + lx;
            xl[i] = (gy >= 0 && gy < Hh && gx >= 0 && gx < Ww) ? xcur[baseP + gy * Ww + gx] : 0.f;
        }
        __syncthreads();
    }
    const int gi = baseP + (oy0 + ty) * Ww + (ox0 + tx);
    float num = rbuf[gi] * pl[(ty + 2) * 24 + (tx + 2)];
    float den1 = 0.f;
    for (int n = 0; n < NDK; n++) {
        float w = 2.f * sdkw[n];
        if (w == 0.f) continue;
        const float* dn = &dkk[n * 25];
        float dKp = 0.f;
        for (int a = 0; a < 5; a++)
            for (int bb = 0; bb < 5; bb++)
                dKp = fmaf(dn[a * 5 + bb], kl[(ty + a) * 24 + (tx + bb)], dKp);
        den1 = fmaf(w, dKp * dKp, den1);
    }
    float den2 = 0.f;
    for (int m = 0; m < NRK; m++) {
        float rp = srpw[m];
        float w2 = srkw[m] * rp * (rp - 1.f);
        if (w2 == 0.f) continue;
        const float* rm = &rkk[m * 25];
        float Rp = 0.f;
        for (int a = 0; a < 5; a++)
            for (int bb = 0; bb < 5; bb++)
                Rp = fmaf(rm[a * 5 + bb], pl[(ty + a) * 24 + (tx + bb)], Rp);
        float fac = 1.f;
        if (rp != 2.f) {
            float v = 0.f;
            for (int a = 0; a < 5; a++)
                for (int bb = 0; bb < 5; bb++)
                    v = fmaf(rm[a * 5 + bb], xl[(ty + a) * 24 + (tx + bb)], v);
            if (tgt) v -= tgt[((size_t)(b * NRK + m)) * CHW + (size_t)c * PLANE + (oy0 + ty) * Ww + (ox0 + tx)];
            fac = powf(fabsf(v) + EPSf, rp - 2.f);
        }
        den2 = fmaf(w2 * fac * Rp, Rp, den2);
    }
    const int blk = c * (TX * TY) + blockIdx.y * TX + blockIdx.x;
    red[tid] = num; __syncthreads();
    for (int s = 128; s > 0; s >>= 1) { if (tid < s) red[tid] += red[tid + s]; __syncthreads(); }
    if (tid == 0) part[((size_t)b * 4 + 0) * BPB + blk] = red[0];
    __syncthreads();
    red[tid] = den1; __syncthreads();
    for (int s = 128; s > 0; s >>= 1) { if (tid < s) red[tid] += red[tid + s]; __syncthreads(); }
    if (tid == 0) part[((size_t)b * 4 + 1) * BPB + blk] = red[0];
    __syncthreads();
    red[tid] = den2; __syncthreads();
    for (int s = 128; s > 0; s >>= 1) { if (tid < s) red[tid] += red[tid + s]; __syncthreads(); }
    if (tid == 0) part[((size_t)b * 4 + 2) * BPB + blk] = red[0];
}

__global__ __launch_bounds__(256)
void k_fin_alpha(const float* __restrict__ part, CgState* st,
                 const int* __restrict__ ncg, int iter)
{
    const int b = blockIdx.x, tid = threadIdx.x;
    __shared__ float red[256];
    if (st[b].done != 0 || iter >= *ncg) { if (tid == 0) st[b].alpha = 0.f; return; }
    float s0 = 0.f, sd = 0.f;
    for (int i = tid; i < BPB; i += 256) {
        s0 += part[((size_t)b * 4 + 0) * BPB + i];
        sd += part[((size_t)b * 4 + 1) * BPB + i] + part[((size_t)b * 4 + 2) * BPB + i];
    }
    red[tid] = s0; __syncthreads();
    for (int s = 128; s > 0; s >>= 1) { if (tid < s) red[tid] += red[tid + s]; __syncthreads(); }
    float num = red[0]; __syncthreads();
    red[tid] = sd; __syncthreads();
    for (int s = 128; s > 0; s >>= 1) { if (tid < s) red[tid] += red[tid + s]; __syncthreads(); }
    if (tid == 0) st[b].alpha = num / (red[0] + 1e-12f);
}

__global__ __launch_bounds__(256)
void k_fin_iter(const float* __restrict__ part, CgState* st,
                const int* __restrict__ ncg, int iter, int mode)
{
    const int b = blockIdx.x, tid = threadIdx.x;
    __shared__ float red[256];
    if (mode == 1 && (st[b].done != 0 || iter >= *ncg)) { if (tid == 0) st[b].pflag = 0; return; }
    float s = 0.f;
    for (int i = tid; i < BPB; i += 256) s += part[((size_t)b * 4 + 0) * BPB + i];
    red[tid] = s; __syncthreads();
    for (int s2 = 128; s2 > 0; s2 >>= 1) { if (tid < s2) red[tid] += red[tid + s2]; __syncthreads(); }
    if (tid == 0) {
        float nrn = red[0];
        if (mode == 0) {
            st[b].rn = nrn; st[b].r0 = nrn; st[b].done = 0; st[b].pflag = 0;
            st[b].beta = 0.f; st[b].alpha = 0.f;
        } else {
            float beta = nrn / (st[b].rn + 1e-20f);
            int conv = (nrn < CGTOL * st[b].r0) ? 1 : 0;
            st[b].beta = beta; st[b].rn = nrn;
            st[b].pflag = conv ? 0 : 1;
            if (conv) st[b].done = 1;
        }
    }
}

// ------------------------- bilateral grid -------------------------
__global__ __launch_bounds__(64)
void k_splat(const float* __restrict__ x, float* __restrict__ grid)
{
    __shared__ float bins[NBn * 2];
    const int tid = threadIdx.y * 8 + threadIdx.x;
    if (tid < NBn * 2) bins[tid] = 0.f;
    __syncthreads();
    const int pz = blockIdx.z;
    const int gy = blockIdx.y, gx = blockIdx.x;
    const int py = gy * 8 + threadIdx.y, px = gx * 8 + threadIdx.x;
    float I = x[(size_t)pz * PLANE + py * Ww + px];
    float Ic = fminf(fmaxf(I, 0.f), 1.f);
    int zi = (int)rintf(Ic * (NBn - 1));   // round-half-even, matches jnp.round
    zi = min(max(zi, 0), NBn - 1);
    atomicAdd(&bins[zi * 2], Ic);
    atomicAdd(&bins[zi * 2 + 1], 1.f);
    __syncthreads();
    if (tid < NBn * 2)
        grid[(size_t)pz * GH * GW * NBn * 2 + ((size_t)gy * GW + gx) * NBn * 2 + tid] = bins[tid];
}

__global__ __launch_bounds__(256)
void k_blur(const float* __restrict__ in, float* __restrict__ out,
            const float* __restrict__ taps, int ntaps, int axis)
{
    const int id = blockIdx.x * 256 + threadIdx.x;
    const int total = Bn * Cn * GH * GW * NBn;
    if (id >= total) return;
    const int z = id % NBn;
    const int x = (id / NBn) % GW;
    const int y = (id / (NBn * GW)) % GH;
    const int p = id / (NBn * GW * GH);
    int coord, lim; long stride;
    if (axis == 0)      { coord = y; lim = GH;  stride = (long)GW * NBn * 2; }
    else if (axis == 1) { coord = x; lim = GW;  stride = NBn * 2; }
    else                { coord = z; lim = NBn; stride = 2; }
    const long base = (((long)(p * GH + y) * GW + x) * NBn + z) * 2;
    const int r = ntaps / 2;
    float a0 = 0.f, a1 = 0.f;
    for (int t = 0; t < ntaps; t++) {
        int cc = coord + t - r;
        if (cc < 0 || cc >= lim) continue;
        float w = taps[t];
        long ofs = base + (long)(cc - coord) * stride;
        a0 = fmaf(w, in[ofs], a0);
        a1 = fmaf(w, in[ofs + 1], a1);
    }
    out[base] = a0; out[base + 1] = a1;
}

__global__ __launch_bounds__(256)
void k_slice(const float* __restrict__ xin, const float* __restrict__ grid,
             float* __restrict__ xout)
{
    const int pz = blockIdx.z;
    const int id = blockIdx.x * 256 + threadIdx.x;
    const int py = id / Ww, px = id % Ww;
    float I = xin[(size_t)pz * PLANE + id];
    float Ic = fminf(fmaxf(I, 0.f), 1.f);
    float yf = (float)py / SS, xf = (float)px / SS, zf = Ic * (NBn - 1);
    int y0 = min(max((int)floorf(yf), 0), GH - 1); int y1 = min(y0 + 1, GH - 1);
    float wy = fminf(fmaxf(yf - (float)y0, 0.f), 1.f);
    int x0 = min(max((int)floorf(xf), 0), GW - 1); int x1 = min(x0 + 1, GW - 1);
    float wx = fminf(fmaxf(xf - (float)x0, 0.f), 1.f);
    int z0 = min(max((int)floorf(zf), 0), NBn - 1); int z1 = min(z0 + 1, NBn - 1);
    float wz = fminf(fmaxf(zf - (float)z0, 0.f), 1.f);
    const float* gp = grid + (size_t)pz * GH * GW * NBn * 2;
    const int   ys[2] = { y0, y1 };  const float wys[2] = { 1.f - wy, wy };
    const int   xs[2] = { x0, x1 };  const float wxs[2] = { 1.f - wx, wx };
    const int   zs[2] = { z0, z1 };  const float wzs[2] = { 1.f - wz, wz };
    float a0 = 0.f, a1 = 0.f;
    for (int iy = 0; iy < 2; iy++)
        for (int ix = 0; ix < 2; ix++)
            for (int iz = 0; iz < 2; iz++) {
                float w = wys[iy] * wxs[ix] * wzs[iz];
                size_t idx = (((size_t)ys[iy] * GW + xs[ix]) * NBn + zs[iz]) * 2;
                a0 = fmaf(w, gp[idx], a0);
                a1 = fmaf(w, gp[idx + 1], a1);
            }
    xout[(size_t)pz * PLANE + id] = a0 / (a1 + 1e-8f);
}

__global__ __launch_bounds__(256)
void k_prior(const float* __restrict__ x, float* __restrict__ tgt,
             const float* __restrict__ rks, const float* __restrict__ thr)
{
    const int pz = blockIdx.z, b = pz / Cn, c = pz % Cn;
    __shared__ float xl[24 * 24];
    __shared__ float rkk[NRK * 25];
    __shared__ float sthr[NRK];
    const int tx = threadIdx.x, ty = threadIdx.y, tid = ty * 16 + tx;
    const int ox0 = blockIdx.x * 16, oy0 = blockIdx.y * 16;
    const int baseP = pz * PLANE;
    for (int i = tid; i < NRK * 25; i += 256) rkk[i] = rks[i];
    if (tid < NRK) sthr[tid] = thr[tid];
    for (int i = tid; i < 24 * 24; i += 256) {
        int ly = i / 24, lx = i % 24;
        int gy = oy0 - 2 + ly, gx = ox0 - 2 + lx;
        xl[i] = (gy >= 0 && gy < Hh && gx >= 0 && gx < Ww) ? x[baseP + gy * Ww + gx] : 0.f;
    }
    __syncthreads();
    const int pix = (oy0 + ty) * Ww + (ox0 + tx);
    for (int m = 0; m < NRK; m++) {
        const float* rm = &rkk[m * 25];
        float v = 0.f;
        for (int a = 0; a < 5; a++)
            for (int bb = 0; bb < 5; bb++)
                v = fmaf(rm[a * 5 + bb], xl[(ty + a) * 24 + (tx + bb)], v);
        float sg = (v > 0.f) ? 1.f : ((v < 0.f) ? -1.f : 0.f);
        tgt[((size_t)(b * NRK + m)) * CHW + (size_t)c * PLANE + pix] =
            sg * fmaxf(fabsf(v) - sthr[m], 0.f);
    }
}

// ------------------------------ host ------------------------------
extern "C" void kernel_launch(void* const* d_in, const int* in_sizes, int n_in,
                              void* d_out, int out_size, void* d_ws, size_t ws_size,
                              hipStream_t stream)
{
    const float* blurred = (const float*)d_in[0];
    const float* kern    = (const float*)d_in[1];
    const float* dks     = (const float*)d_in[2];
    const float* dkw     = (const float*)d_in[3];
    const float* rks     = (const float*)d_in[4];
    const float* rkw     = (const float*)d_in[5];
    const float* rpw     = (const float*)d_in[6];
    const float* fs      = (const float*)d_in[7];
    const float* fr      = (const float*)d_in[8];
    const float* thr     = (const float*)d_in[9];
    const int*   ncg     = (const int*)d_in[10];
    (void)in_sizes; (void)n_in; (void)out_size; (void)ws_size;

    float* w = (float*)d_ws;
    size_t off = 0;
    auto alloc = [&](size_t n) { float* p = w + off; off += n; return p; };
    float* xb[2] = { alloc((size_t)Bn * CHW), alloc((size_t)Bn * CHW) };
    float* pb[2] = { alloc((size_t)Bn * CHW), alloc((size_t)Bn * CHW) };
    float* rb   = alloc((size_t)Bn * CHW);
    float* kb   = alloc((size_t)Bn * CHW);
    float* ub   = alloc((size_t)Bn * CHW);
    float* tg   = alloc((size_t)Bn * NRK * CHW);
    float* g0   = alloc((size_t)Bn * Cn * GH * GW * NBn * 2);
    float* g1   = alloc((size_t)Bn * Cn * GH * GW * NBn * 2);
    float* part = alloc((size_t)Bn * 4 * BPB);
    CgState* st = (CgState*)(w + off); off += Bn * 8;

    dim3 tb(TIL, TIL), grd(TX, TY, Bn * Cn);
    int xi = 0, pi = 0;

    auto run_cg = [&](int idx, const float* tgt, bool firstFromBlurred) {
        const float* dks_i = dks + (size_t)idx * NDK * 25;
        const float* dkw_i = dkw + (size_t)idx * NDK;
        const float* rks_i = rks + (size_t)idx * NRK * 25;
        const float* rkw_i = rkw + (size_t)idx * NRK;
        const float* rpw_i = rpw + (size_t)idx * NRK;
        // ---- init: g = grad(x0); r = p = -g; rn = r0 = ||r||^2 ----
        if (firstFromBlurred) {
            k_corr15<<<grd, tb, 0, stream>>>(blurred, nullptr, xb[0], blurred, kb, kern, st, ncg, 0, 0);
            xi = 0;
        } else {
            k_corr15<<<grd, tb, 0, stream>>>(xb[xi], nullptr, nullptr, blurred, kb, kern, st, ncg, 0, 0);
        }
        k_u<<<grd, tb, 0, stream>>>(kb, ub, dks_i, dkw_i, st, ncg, 0, 0);
        pi = 0;
        k_D<<<grd, tb, 0, stream>>>(ub, xb[xi], tgt, rb, pb[0], kern, rks_i, rkw_i, rpw_i, part, st, ncg, 0, 0);
        k_fin_iter<<<Bn, 256, 0, stream>>>(part, st, ncg, 0, 0);
        // ---- iterations ----
        for (int i = 0; i < NITER; i++) {
            k_corr15<<<grd, tb, 0, stream>>>(pb[pi], rb, pb[1 - pi], nullptr, kb, kern, st, ncg, i, 2);
            pi = 1 - pi;
            k_alpha<<<grd, tb, 0, stream>>>(kb, pb[pi], rb, xb[xi], tgt, dks_i, dkw_i,
                                            rks_i, rkw_i, rpw_i, part, st, ncg, i);
            k_fin_alpha<<<Bn, 256, 0, stream>>>(part, st, ncg, i);
            k_corr15<<<grd, tb, 0, stream>>>(xb[xi], pb[pi], xb[1 - xi], blurred, kb, kern, st, ncg, i, 1);
            xi = 1 - xi;
            k_u<<<grd, tb, 0, stream>>>(kb, ub, dks_i, dkw_i, st, ncg, i, 1);
            k_D<<<grd, tb, 0, stream>>>(ub, xb[xi], tgt, rb, nullptr, kern, rks_i, rkw_i, rpw_i, part, st, ncg, i, 1);
            k_fin_iter<<<Bn, 256, 0, stream>>>(part, st, ncg, i, 1);
        }
    };

    // CG solve 1 (idx 0, zero reg targets)
    run_cg(0, nullptr, true);

    // bilateral grid stage (stage 0)
    dim3 sb(8, 8), sg(GW, GH, Bn * Cn);
    k_splat<<<sg, sb, 0, stream>>>(xb[xi], g0);
    const int totalg = Bn * Cn * GH * GW * NBn;
    k_blur<<<(totalg + 255) / 256, 256, 0, stream>>>(g0, g1, fs, 11, 0);
    k_blur<<<(totalg + 255) / 256, 256, 0, stream>>>(g1, g0, fs, 11, 1);
    k_blur<<<(totalg + 255) / 256, 256, 0, stream>>>(g0, g1, fr, 5, 2);
    k_slice<<<dim3(PLANE / 256, 1, Bn * Cn), 256, 0, stream>>>(xb[xi], g1, xb[1 - xi]);
    xi = 1 - xi;

    // shrinkage prior -> reg targets (uses reg_kernels[1], thresholds[0])
    k_prior<<<grd, tb, 0, stream>>>(xb[xi], tg, rks + NRK * 25, thr);

    // CG solve 2 (idx 1, with targets)
    run_cg(1, tg, false);

    hipMemcpyAsync(d_out, xb[xi], (size_t)Bn * CHW * sizeof(float),
                   hipMemcpyDeviceToDevice, stream);
}

// Round 2
// 1754.680 us; speedup vs baseline: 2.1539x; 2.1539x over previous
//
#include <hip/hip_runtime.h>

// ---------------- problem constants (match setup_inputs) ----------------
constexpr int Bn = 2, Cn = 3, Hh = 512, Ww = 512;
constexpr int KS = 15, KR = 7;          // PSF kernel
constexpr int NDK = 6, NRK = 5;         // data / reg bank sizes (5x5, r=2)
constexpr int GH = 64, GW = 64, NBn = 9, SS = 8;  // bilateral grid
constexpr float EPSf = 1e-8f;
constexpr float CGTOL = 1e-4f;
constexpr int PLANE = Hh * Ww;
constexpr int CHW = Cn * PLANE;
constexpr int BX = 64, BY = 16;         // conv output tile (per 256-thread block, 4 px/thread in x)
constexpr int GXc = Ww / BX, GYc = Hh / BY;   // 8 x 32
constexpr int PB = GXc * GYc * Cn;      // 768 partial-blocks per batch
constexpr int SA = 80, THt = 30;        // 15x15 halo tile: 78x30 data, stride 80
constexpr int S2W = 72, S2H = 24;       // 5x5-bank src tile (halo 4): 72x24
constexpr int PHW = 68, PHH = 20;       // 5x5-bank mid tile (halo 2): 68x20
constexpr int NITER = 5;                // host-side launch count; device guards vs *ncg

struct CgState { float alpha, beta, rn, r0; int done, pflag; int pad0, pad1; };

__device__ __forceinline__ float blockReduce(float v, float* red, int tid) {
    red[tid] = v; __syncthreads();
    for (int s = 128; s > 0; s >>= 1) { if (tid < s) red[tid] += red[tid + s]; __syncthreads(); }
    float r = red[0]; __syncthreads();
    return r;
}

// ---------------------------------------------------------------------
// k_conv15: 15x15 correlation, 64x16 tile, 4 px/thread.
// mode 0: v = src, copy v -> xcopy (interior), out = corr(v) - sub
// mode 1: v = src,                          out = corr(v) - sub
// mode 2: v = p_cur = pflag ? r + beta*p : p ; out = corr(v);
//         num = sum_interior r*p_cur -> part slot0
// ---------------------------------------------------------------------
__global__ __launch_bounds__(256)
void k_conv15(const float* __restrict__ src, const float* __restrict__ rb,
              const float* __restrict__ pbuf, float* __restrict__ xcopy,
              const float* __restrict__ sub, float* __restrict__ out,
              const float* __restrict__ kernB, float* __restrict__ part,
              const CgState* __restrict__ st, const int* __restrict__ ncg,
              int iter, int mode)
{
    const int pz = blockIdx.z, b = pz / Cn, c = pz % Cn;
    const CgState s = st[b];
    if (mode == 2 && (s.done != 0 || iter >= *ncg)) return;
    __shared__ __align__(16) float tile[SA * THt];
    __shared__ __align__(16) float kkp[15 * 16];
    __shared__ float red[256];
    const int tx = threadIdx.x, ty = threadIdx.y, tid = ty * 16 + tx;
    const int ox0 = blockIdx.x * BX, oy0 = blockIdx.y * BY;
    const int baseP = pz * PLANE;
    const float beta = s.beta; const int pf = s.pflag;

    const float* kp = kernB + b * 225;
    for (int i = tid; i < 225; i += 256) kkp[(i / 15) * 16 + (i % 15)] = kp[i];

    float nm = 0.f;
    for (int i = tid; i < 78 * THt; i += 256) {
        int ly = i / 78, lx = i % 78;
        int gy = oy0 - KR + ly, gx = ox0 - KR + lx;
        float v = 0.f;
        if (gy >= 0 && gy < Hh && gx >= 0 && gx < Ww) {
            int gi = baseP + gy * Ww + gx;
            if (mode == 2) {
                float rv = rb[gi], pv = pbuf[gi];
                v = pf ? fmaf(beta, pv, rv) : pv;
                if (ly >= KR && ly < KR + BY && lx >= KR && lx < KR + BX)
                    nm = fmaf(rv, v, nm);
            } else {
                v = src[gi];
                if (mode == 0 && ly >= KR && ly < KR + BY && lx >= KR && lx < KR + BX)
                    xcopy[gi] = v;
            }
        }
        tile[ly * SA + lx] = v;
    }
    __syncthreads();

    const int colbase = tx * 4;
    float a0 = 0.f, a1 = 0.f, a2 = 0.f, a3 = 0.f;
    for (int i = 0; i < KS; i++) {
        const float4* rp4 = reinterpret_cast<const float4*>(&tile[(ty + i) * SA + colbase]);
        float f[20];
        #pragma unroll
        for (int s5 = 0; s5 < 5; s5++) {
            float4 w4 = rp4[s5];
            f[s5 * 4] = w4.x; f[s5 * 4 + 1] = w4.y; f[s5 * 4 + 2] = w4.z; f[s5 * 4 + 3] = w4.w;
        }
        const float4* kr4 = reinterpret_cast<const float4*>(&kkp[i * 16]);
        float kf[16];
        #pragma unroll
        for (int s5 = 0; s5 < 4; s5++) {
            float4 k4 = kr4[s5];
            kf[s5 * 4] = k4.x; kf[s5 * 4 + 1] = k4.y; kf[s5 * 4 + 2] = k4.z; kf[s5 * 4 + 3] = k4.w;
        }
        #pragma unroll
        for (int j = 0; j < KS; j++) {
            float kv = kf[j];
            a0 = fmaf(kv, f[j], a0); a1 = fmaf(kv, f[j + 1], a1);
            a2 = fmaf(kv, f[j + 2], a2); a3 = fmaf(kv, f[j + 3], a3);
        }
    }
    const int gi = baseP + (oy0 + ty) * Ww + ox0 + colbase;
    if (sub) {
        float4 sv = *reinterpret_cast<const float4*>(&sub[gi]);
        a0 -= sv.x; a1 -= sv.y; a2 -= sv.z; a3 -= sv.w;
    }
    *reinterpret_cast<float4*>(&out[gi]) = make_float4(a0, a1, a2, a3);
    if (mode == 2) {
        float tot = blockReduce(nm, red, tid);
        if (tid == 0) {
            int blk = c * (GXc * GYc) + blockIdx.y * GXc + blockIdx.x;
            part[((size_t)b * 4 + 0) * PB + blk] = tot;
        }
    }
}

// ---------------------------------------------------------------------
// k_bank: t = sum_n 2*dkw_n * bankT_n(bank_n(s))   (d zeroed outside image)
// ---------------------------------------------------------------------
__global__ __launch_bounds__(256)
void k_bank(const float* __restrict__ sbuf, float* __restrict__ tbuf,
            const float* __restrict__ dks, const float* __restrict__ dkw,
            const CgState* __restrict__ st, const int* __restrict__ ncg,
            int iter, int mode)
{
    const int pz = blockIdx.z, b = pz / Cn;
    if (mode == 1 && (st[b].done != 0 || iter >= *ncg)) return;
    __shared__ float sl[S2W * S2H];
    __shared__ float dl[PHW * PHH];
    __shared__ float dkk[NDK * 25];
    __shared__ float dww[NDK];
    const int tx = threadIdx.x, ty = threadIdx.y, tid = ty * 16 + tx;
    const int ox0 = blockIdx.x * BX, oy0 = blockIdx.y * BY;
    const int baseP = pz * PLANE;
    for (int i = tid; i < NDK * 25; i += 256) dkk[i] = dks[i];
    if (tid < NDK) dww[tid] = dkw[tid];
    for (int i = tid; i < S2W * S2H; i += 256) {
        int ly = i / S2W, lx = i % S2W;
        int gy = oy0 - 4 + ly, gx = ox0 - 4 + lx;
        sl[i] = (gy >= 0 && gy < Hh && gx >= 0 && gx < Ww) ? sbuf[baseP + gy * Ww + gx] : 0.f;
    }
    __syncthreads();
    const int colbase = tx * 4;
    float t0 = 0.f, t1 = 0.f, t2 = 0.f, t3 = 0.f;
    for (int n = 0; n < NDK; n++) {
        float wn = 2.f * dww[n];
        if (wn == 0.f) continue;   // uniform across block
        float dnr[25];
        #pragma unroll
        for (int q = 0; q < 25; q++) dnr[q] = dkk[n * 25 + q];
        for (int i = tid; i < PHW * PHH; i += 256) {
            int zy = i / PHW, zx = i % PHW;
            int gy = oy0 - 2 + zy, gx = ox0 - 2 + zx;
            float d = 0.f;
            if (gy >= 0 && gy < Hh && gx >= 0 && gx < Ww) {
                #pragma unroll
                for (int a = 0; a < 5; a++)
                    #pragma unroll
                    for (int bb = 0; bb < 5; bb++)
                        d = fmaf(dnr[a * 5 + bb], sl[(zy + a) * S2W + zx + bb], d);
            }
            dl[i] = d;
        }
        __syncthreads();
        float c0 = 0.f, c1 = 0.f, c2 = 0.f, c3 = 0.f;
        #pragma unroll
        for (int a = 0; a < 5; a++)
            #pragma unroll
            for (int bb = 0; bb < 5; bb++) {
                float kv = dnr[(4 - a) * 5 + (4 - bb)];
                int base = (ty + a) * PHW + colbase + bb;
                c0 = fmaf(kv, dl[base], c0); c1 = fmaf(kv, dl[base + 1], c1);
                c2 = fmaf(kv, dl[base + 2], c2); c3 = fmaf(kv, dl[base + 3], c3);
            }
        t0 = fmaf(wn, c0, t0); t1 = fmaf(wn, c1, t1);
        t2 = fmaf(wn, c2, t2); t3 = fmaf(wn, c3, t3);
        __syncthreads();
    }
    const int gi = baseP + (oy0 + ty) * Ww + ox0 + colbase;
    *reinterpret_cast<float4*>(&tbuf[gi]) = make_float4(t0, t1, t2, t3);
}

// ---------------------------------------------------------------------
// k_grad:
// mode 0 (GRAD): g = corr15T(wbuf) + sum_m bankT(rkw*rp*sign(v)(|v|+EPS)^(rp-1)),
//                v = bank_m(x) - tgt_m ;  write r=-g, p=r ; slot2 = ||r||^2
// mode 1 (HESS): q = corr15T(wbuf) + sum_m bankT(rkw*rp*(rp-1)*fac*bank_m(p_cur)),
//                p_cur = pflag ? r+beta*p : p ; write q ; slot1 = sum p_cur*q
// ---------------------------------------------------------------------
__global__ __launch_bounds__(256)
void k_grad(const float* __restrict__ wbuf, const float* __restrict__ xg,
            const float* __restrict__ rb, const float* __restrict__ pbuf,
            const float* __restrict__ tgt, float* __restrict__ outb,
            float* __restrict__ pout, const float* __restrict__ kernB,
            const float* __restrict__ rks, const float* __restrict__ rkw,
            const float* __restrict__ rpw, float* __restrict__ part,
            const CgState* __restrict__ st, const int* __restrict__ ncg,
            int iter, int mode)
{
    const int pz = blockIdx.z, b = pz / Cn, c = pz % Cn;
    const CgState s = st[b];
    if (mode == 1 && (s.done != 0 || iter >= *ncg)) return;
    __shared__ __align__(16) float wt[SA * THt];
    __shared__ float s2[S2W * S2H];
    __shared__ float ph[PHW * PHH];
    __shared__ __align__(16) float kkp[15 * 16];     // flipped PSF
    __shared__ float rk5[NRK * 25];
    __shared__ float srkw[NRK], srpw[NRK];
    __shared__ float red[256];
    const int tx = threadIdx.x, ty = threadIdx.y, tid = ty * 16 + tx;
    const int ox0 = blockIdx.x * BX, oy0 = blockIdx.y * BY;
    const int baseP = pz * PLANE;
    const float beta = s.beta; const int pf = s.pflag;

    const float* kp = kernB + b * 225;
    for (int i = tid; i < 225; i += 256) kkp[(i / 15) * 16 + (i % 15)] = kp[224 - i];
    for (int i = tid; i < NRK * 25; i += 256) rk5[i] = rks[i];
    if (tid < NRK) { srkw[tid] = rkw[tid]; srpw[tid] = rpw[tid]; }

    for (int i = tid; i < 78 * THt; i += 256) {
        int ly = i / 78, lx = i % 78;
        int gy = oy0 - KR + ly, gx = ox0 - KR + lx;
        wt[ly * SA + lx] = (gy >= 0 && gy < Hh && gx >= 0 && gx < Ww)
                           ? wbuf[baseP + gy * Ww + gx] : 0.f;
    }
    for (int i = tid; i < S2W * S2H; i += 256) {
        int ly = i / S2W, lx = i % S2W;
        int gy = oy0 - 4 + ly, gx = ox0 - 4 + lx;
        float v = 0.f;
        if (gy >= 0 && gy < Hh && gx >= 0 && gx < Ww) {
            int gi = baseP + gy * Ww + gx;
            if (mode == 0) v = xg[gi];
            else { float rv = rb[gi], pv = pbuf[gi]; v = pf ? fmaf(beta, pv, rv) : pv; }
        }
        s2[i] = v;
    }
    __syncthreads();

    const int colbase = tx * 4;
    float a0 = 0.f, a1 = 0.f, a2 = 0.f, a3 = 0.f;
    for (int i = 0; i < KS; i++) {
        const float4* rp4 = reinterpret_cast<const float4*>(&wt[(ty + i) * SA + colbase]);
        float f[20];
        #pragma unroll
        for (int s5 = 0; s5 < 5; s5++) {
            float4 w4 = rp4[s5];
            f[s5 * 4] = w4.x; f[s5 * 4 + 1] = w4.y; f[s5 * 4 + 2] = w4.z; f[s5 * 4 + 3] = w4.w;
        }
        const float4* kr4 = reinterpret_cast<const float4*>(&kkp[i * 16]);
        float kf[16];
        #pragma unroll
        for (int s5 = 0; s5 < 4; s5++) {
            float4 k4 = kr4[s5];
            kf[s5 * 4] = k4.x; kf[s5 * 4 + 1] = k4.y; kf[s5 * 4 + 2] = k4.z; kf[s5 * 4 + 3] = k4.w;
        }
        #pragma unroll
        for (int j = 0; j < KS; j++) {
            float kv = kf[j];
            a0 = fmaf(kv, f[j], a0); a1 = fmaf(kv, f[j + 1], a1);
            a2 = fmaf(kv, f[j + 2], a2); a3 = fmaf(kv, f[j + 3], a3);
        }
    }

    for (int m = 0; m < NRK; m++) {
        float wm = srkw[m], rp = srpw[m];
        if (wm == 0.f) continue;  // uniform
        float rmr[25];
        #pragma unroll
        for (int q = 0; q < 25; q++) rmr[q] = rk5[m * 25 + q];
        const float* tgm = tgt ? tgt + ((size_t)(b * NRK + m)) * CHW + (size_t)c * PLANE : nullptr;
        for (int i = tid; i < PHW * PHH; i += 256) {
            int zy = i / PHW, zx = i % PHW;
            int gy = oy0 - 2 + zy, gx = ox0 - 2 + zx;
            float val = 0.f;
            if (gy >= 0 && gy < Hh && gx >= 0 && gx < Ww) {
                float v = 0.f;
                #pragma unroll
                for (int a = 0; a < 5; a++)
                    #pragma unroll
                    for (int bb = 0; bb < 5; bb++)
                        v = fmaf(rmr[a * 5 + bb], s2[(zy + a) * S2W + zx + bb], v);
                if (mode == 0) {
                    if (tgm) v -= tgm[gy * Ww + gx];
                    float sg = (v > 0.f) ? 1.f : ((v < 0.f) ? -1.f : 0.f);
                    float av = fabsf(v) + EPSf;
                    float pw = (rp == 2.f) ? av : powf(av, rp - 1.f);
                    val = wm * rp * sg * pw;
                } else {
                    float fac = 1.f;
                    if (rp != 2.f) {   // Gauss-Newton weight from current x (cold path)
                        float vx = 0.f;
                        for (int a = 0; a < 5; a++)
                            for (int bb = 0; bb < 5; bb++) {
                                int yy = gy - 2 + a, xx = gx - 2 + bb;
                                if (yy >= 0 && yy < Hh && xx >= 0 && xx < Ww)
                                    vx = fmaf(rmr[a * 5 + bb], xg[baseP + yy * Ww + xx], vx);
                            }
                        if (tgm) vx -= tgm[gy * Ww + gx];
                        fac = powf(fabsf(vx) + EPSf, rp - 2.f);
                    }
                    val = wm * rp * (rp - 1.f) * fac * v;
                }
            }
            ph[i] = val;
        }
        __syncthreads();
        #pragma unroll
        for (int a = 0; a < 5; a++)
            #pragma unroll
            for (int bb = 0; bb < 5; bb++) {
                float kv = rmr[(4 - a) * 5 + (4 - bb)];
                int base = (ty + a) * PHW + colbase + bb;
                a0 = fmaf(kv, ph[base], a0); a1 = fmaf(kv, ph[base + 1], a1);
                a2 = fmaf(kv, ph[base + 2], a2); a3 = fmaf(kv, ph[base + 3], a3);
            }
        __syncthreads();
    }

    const int gi = baseP + (oy0 + ty) * Ww + ox0 + colbase;
    float redv;
    if (mode == 0) {
        float r0v = -a0, r1v = -a1, r2v = -a2, r3v = -a3;
        float4 rv4 = make_float4(r0v, r1v, r2v, r3v);
        *reinterpret_cast<float4*>(&outb[gi]) = rv4;
        *reinterpret_cast<float4*>(&pout[gi]) = rv4;
        redv = r0v * r0v + r1v * r1v + r2v * r2v + r3v * r3v;
    } else {
        *reinterpret_cast<float4*>(&outb[gi]) = make_float4(a0, a1, a2, a3);
        int li = (ty + 4) * S2W + colbase + 4;
        redv = s2[li] * a0 + s2[li + 1] * a1 + s2[li + 2] * a2 + s2[li + 3] * a3;
    }
    float tot = blockReduce(redv, red, tid);
    if (tid == 0) {
        int blk = c * (GXc * GYc) + blockIdx.y * GXc + blockIdx.x;
        int slot = (mode == 0) ? 2 : 1;
        part[((size_t)b * 4 + slot) * PB + blk] = tot;
    }
}

// ---------------------------------------------------------------------
// k_axpy: p_cur = pflag ? r+beta*p : p ; x += alpha*p_cur ; r -= alpha*q ;
//         persist p = p_cur ; slot2 = ||r_new||^2
// ---------------------------------------------------------------------
__global__ __launch_bounds__(256)
void k_axpy(float4* __restrict__ x, float4* __restrict__ r, float4* __restrict__ p,
            const float4* __restrict__ q, float* __restrict__ part,
            const CgState* __restrict__ st, const int* __restrict__ ncg, int iter)
{
    const int b = blockIdx.y;
    const CgState s = st[b];
    if (s.done != 0 || iter >= *ncg) return;
    __shared__ float red[256];
    const int tid = threadIdx.x;
    const int idx = b * (CHW / 4) + blockIdx.x * 256 + tid;
    float4 pv = p[idx], rv = r[idx], qv = q[idx], xv = x[idx];
    float4 pc;
    if (s.pflag) {
        pc.x = fmaf(s.beta, pv.x, rv.x); pc.y = fmaf(s.beta, pv.y, rv.y);
        pc.z = fmaf(s.beta, pv.z, rv.z); pc.w = fmaf(s.beta, pv.w, rv.w);
    } else pc = pv;
    xv.x = fmaf(s.alpha, pc.x, xv.x); xv.y = fmaf(s.alpha, pc.y, xv.y);
    xv.z = fmaf(s.alpha, pc.z, xv.z); xv.w = fmaf(s.alpha, pc.w, xv.w);
    rv.x = fmaf(-s.alpha, qv.x, rv.x); rv.y = fmaf(-s.alpha, qv.y, rv.y);
    rv.z = fmaf(-s.alpha, qv.z, rv.z); rv.w = fmaf(-s.alpha, qv.w, rv.w);
    x[idx] = xv; r[idx] = rv; p[idx] = pc;
    float nr = rv.x * rv.x + rv.y * rv.y + rv.z * rv.z + rv.w * rv.w;
    float tot = blockReduce(nr, red, tid);
    if (tid == 0) part[((size_t)b * 4 + 2) * PB + blockIdx.x] = tot;
}

__global__ __launch_bounds__(256)
void k_fin_alpha(const float* __restrict__ part, CgState* st,
                 const int* __restrict__ ncg, int iter)
{
    const int b = blockIdx.x, tid = threadIdx.x;
    __shared__ float red[256];
    if (st[b].done != 0 || iter >= *ncg) { if (tid == 0) st[b].alpha = 0.f; return; }
    float sn = 0.f, sd = 0.f;
    for (int i = tid; i < PB; i += 256) {
        sn += part[((size_t)b * 4 + 0) * PB + i];
        sd += part[((size_t)b * 4 + 1) * PB + i];
    }
    float num = blockReduce(sn, red, tid);
    float den = blockReduce(sd, red, tid);
    if (tid == 0) st[b].alpha = num / (den + 1e-12f);
}

__global__ __launch_bounds__(256)
void k_fin_iter(const float* __restrict__ part, CgState* st,
                const int* __restrict__ ncg, int iter, int mode)
{
    const int b = blockIdx.x, tid = threadIdx.x;
    __shared__ float red[256];
    if (mode == 1 && (st[b].done != 0 || iter >= *ncg)) { if (tid == 0) st[b].pflag = 0; return; }
    float s = 0.f;
    for (int i = tid; i < PB; i += 256) s += part[((size_t)b * 4 + 2) * PB + i];
    float nrn = blockReduce(s, red, tid);
    if (tid == 0) {
        if (mode == 0) {
            st[b].rn = nrn; st[b].r0 = nrn; st[b].done = 0; st[b].pflag = 0;
            st[b].beta = 0.f; st[b].alpha = 0.f;
        } else {
            float beta = nrn / (st[b].rn + 1e-20f);
            int conv = (nrn < CGTOL * st[b].r0) ? 1 : 0;
            st[b].beta = beta; st[b].rn = nrn;
            st[b].pflag = conv ? 0 : 1;
            if (conv) st[b].done = 1;
        }
    }
}

// ------------------------- bilateral grid -------------------------
__global__ __launch_bounds__(64)
void k_splat(const float* __restrict__ x, float* __restrict__ grid)
{
    __shared__ float bins[NBn * 2];
    const int tid = threadIdx.y * 8 + threadIdx.x;
    if (tid < NBn * 2) bins[tid] = 0.f;
    __syncthreads();
    const int pz = blockIdx.z;
    const int gy = blockIdx.y, gx = blockIdx.x;
    const int py = gy * 8 + threadIdx.y, px = gx * 8 + threadIdx.x;
    float I = x[(size_t)pz * PLANE + py * Ww + px];
    float Ic = fminf(fmaxf(I, 0.f), 1.f);
    int zi = (int)rintf(Ic * (NBn - 1));
    zi = min(max(zi, 0), NBn - 1);
    atomicAdd(&bins[zi * 2], Ic);
    atomicAdd(&bins[zi * 2 + 1], 1.f);
    __syncthreads();
    if (tid < NBn * 2)
        grid[(size_t)pz * GH * GW * NBn * 2 + ((size_t)gy * GW + gx) * NBn * 2 + tid] = bins[tid];
}

__global__ __launch_bounds__(256)
void k_blur(const float* __restrict__ in, float* __restrict__ out,
            const float* __restrict__ taps, int ntaps, int axis)
{
    const int id = blockIdx.x * 256 + threadIdx.x;
    const int total = Bn * Cn * GH * GW * NBn;
    if (id >= total) return;
    const int z = id % NBn;
    const int x = (id / NBn) % GW;
    const int y = (id / (NBn * GW)) % GH;
    const int p = id / (NBn * GW * GH);
    int coord, lim; long stride;
    if (axis == 0)      { coord = y; lim = GH;  stride = (long)GW * NBn * 2; }
    else if (axis == 1) { coord = x; lim = GW;  stride = NBn * 2; }
    else                { coord = z; lim = NBn; stride = 2; }
    const long base = (((long)(p * GH + y) * GW + x) * NBn + z) * 2;
    const int r = ntaps / 2;
    float a0 = 0.f, a1 = 0.f;
    for (int t = 0; t < ntaps; t++) {
        int cc = coord + t - r;
        if (cc < 0 || cc >= lim) continue;
        float w = taps[t];
        long ofs = base + (long)(cc - coord) * stride;
        a0 = fmaf(w, in[ofs], a0);
        a1 = fmaf(w, in[ofs + 1], a1);
    }
    out[base] = a0; out[base + 1] = a1;
}

__global__ __launch_bounds__(256)
void k_slice(const float* __restrict__ xin, const float* __restrict__ grid,
             float* __restrict__ xout)
{
    const int pz = blockIdx.z;
    const int id = blockIdx.x * 256 + threadIdx.x;
    const int py = id / Ww, px = id % Ww;
    float I = xin[(size_t)pz * PLANE + id];
    float Ic = fminf(fmaxf(I, 0.f), 1.f);
    float yf = (float)py / SS, xf = (float)px / SS, zf = Ic * (NBn - 1);
    int y0 = min(max((int)floorf(yf), 0), GH - 1); int y1 = min(y0 + 1, GH - 1);
    float wy = fminf(fmaxf(yf - (float)y0, 0.f), 1.f);
    int x0 = min(max((int)floorf(xf), 0), GW - 1); int x1 = min(x0 + 1, GW - 1);
    float wx = fminf(fmaxf(xf - (float)x0, 0.f), 1.f);
    int z0 = min(max((int)floorf(zf), 0), NBn - 1); int z1 = min(z0 + 1, NBn - 1);
    float wz = fminf(fmaxf(zf - (float)z0, 0.f), 1.f);
    const float* gp = grid + (size_t)pz * GH * GW * NBn * 2;
    const int   ys[2] = { y0, y1 };  const float wys[2] = { 1.f - wy, wy };
    const int   xs[2] = { x0, x1 };  const float wxs[2] = { 1.f - wx, wx };
    const int   zs[2] = { z0, z1 };  const float wzs[2] = { 1.f - wz, wz };
    float a0 = 0.f, a1 = 0.f;
    for (int iy = 0; iy < 2; iy++)
        for (int ix = 0; ix < 2; ix++)
            for (int iz = 0; iz < 2; iz++) {
                float w = wys[iy] * wxs[ix] * wzs[iz];
                size_t idx = (((size_t)ys[iy] * GW + xs[ix]) * NBn + zs[iz]) * 2;
                a0 = fmaf(w, gp[idx], a0);
                a1 = fmaf(w, gp[idx + 1], a1);
            }
    xout[(size_t)pz * PLANE + id] = a0 / (a1 + 1e-8f);
}

__global__ __launch_bounds__(256)
void k_prior(const float* __restrict__ x, float* __restrict__ tgt,
             const float* __restrict__ rks, const float* __restrict__ thr)
{
    const int pz = blockIdx.z, b = pz / Cn, c = pz % Cn;
    __shared__ float xl[24 * 24];
    __shared__ float rkk[NRK * 25];
    __shared__ float sthr[NRK];
    const int tx = threadIdx.x, ty = threadIdx.y, tid = ty * 16 + tx;
    const int ox0 = blockIdx.x * 16, oy0 = blockIdx.y * 16;
    const int baseP = pz * PLANE;
    for (int i = tid; i < NRK * 25; i += 256) rkk[i] = rks[i];
    if (tid < NRK) sthr[tid] = thr[tid];
    for (int i = tid; i < 24 * 24; i += 256) {
        int ly = i / 24, lx = i % 24;
        int gy = oy0 - 2 + ly, gx = ox0 - 2 + lx;
        xl[i] = (gy >= 0 && gy < Hh && gx >= 0 && gx < Ww) ? x[baseP + gy * Ww + gx] : 0.f;
    }
    __syncthreads();
    const int pix = (oy0 + ty) * Ww + (ox0 + tx);
    for (int m = 0; m < NRK; m++) {
        const float* rm = &rkk[m * 25];
        float v = 0.f;
        #pragma unroll
        for (int a = 0; a < 5; a++)
            #pragma unroll
            for (int bb = 0; bb < 5; bb++)
                v = fmaf(rm[a * 5 + bb], xl[(ty + a) * 24 + (tx + bb)], v);
        float sg = (v > 0.f) ? 1.f : ((v < 0.f) ? -1.f : 0.f);
        tgt[((size_t)(b * NRK + m)) * CHW + (size_t)c * PLANE + pix] =
            sg * fmaxf(fabsf(v) - sthr[m], 0.f);
    }
}

// ------------------------------ host ------------------------------
extern "C" void kernel_launch(void* const* d_in, const int* in_sizes, int n_in,
                              void* d_out, int out_size, void* d_ws, size_t ws_size,
                              hipStream_t stream)
{
    const float* blurred = (const float*)d_in[0];
    const float* kern    = (const float*)d_in[1];
    const float* dks     = (const float*)d_in[2];
    const float* dkw     = (const float*)d_in[3];
    const float* rks     = (const float*)d_in[4];
    const float* rkw     = (const float*)d_in[5];
    const float* rpw     = (const float*)d_in[6];
    const float* fs      = (const float*)d_in[7];
    const float* fr      = (const float*)d_in[8];
    const float* thr     = (const float*)d_in[9];
    const int*   ncg     = (const int*)d_in[10];
    (void)in_sizes; (void)n_in; (void)out_size; (void)ws_size;

    float* w = (float*)d_ws;
    size_t off = 0;
    auto alloc = [&](size_t n) { float* p = w + off; off += n; return p; };
    float* xb   = alloc((size_t)Bn * CHW);
    float* pbuf = alloc((size_t)Bn * CHW);
    float* rbuf = alloc((size_t)Bn * CHW);
    float* kx   = alloc((size_t)Bn * CHW);
    float* wb   = alloc((size_t)Bn * CHW);
    float* qb   = alloc((size_t)Bn * CHW);
    float* tg   = alloc((size_t)Bn * NRK * CHW);
    float* g0   = alloc((size_t)Bn * Cn * GH * GW * NBn * 2);
    float* g1   = alloc((size_t)Bn * Cn * GH * GW * NBn * 2);
    float* part = alloc((size_t)Bn * 4 * PB);
    CgState* st = (CgState*)(w + off); off += Bn * 8;

    dim3 tb(16, 16), grd(GXc, GYc, Bn * Cn);

    auto solve = [&](int idx, const float* tgt, int initmode) {
        const float* dks_i = dks + (size_t)idx * NDK * 25;
        const float* dkw_i = dkw + (size_t)idx * NDK;
        const float* rks_i = rks + (size_t)idx * NRK * 25;
        const float* rkw_i = rkw + (size_t)idx * NRK;
        const float* rpw_i = rpw + (size_t)idx * NRK;
        // init: Kx-b -> bank -> gradient (r = p = -g, r0 = ||r||^2)
        k_conv15<<<grd, tb, 0, stream>>>(initmode == 0 ? blurred : xb, nullptr, nullptr,
                                         initmode == 0 ? xb : nullptr, blurred, kx, kern,
                                         nullptr, st, ncg, 0, initmode == 0 ? 0 : 1);
        k_bank<<<grd, tb, 0, stream>>>(kx, wb, dks_i, dkw_i, st, ncg, 0, 0);
        k_grad<<<grd, tb, 0, stream>>>(wb, xb, nullptr, nullptr, tgt, rbuf, pbuf, kern,
                                       rks_i, rkw_i, rpw_i, part, st, ncg, 0, 0);
        k_fin_iter<<<Bn, 256, 0, stream>>>(part, st, ncg, 0, 0);
        for (int i = 0; i < NITER; i++) {
            // q = A * p_cur ; num = r.p_cur ; den = p_cur.q
            k_conv15<<<grd, tb, 0, stream>>>(nullptr, rbuf, pbuf, nullptr, nullptr, kx, kern,
                                             part, st, ncg, i, 2);
            k_bank<<<grd, tb, 0, stream>>>(kx, wb, dks_i, dkw_i, st, ncg, i, 1);
            k_grad<<<grd, tb, 0, stream>>>(wb, xb, rbuf, pbuf, tgt, qb, nullptr, kern,
                                           rks_i, rkw_i, rpw_i, part, st, ncg, i, 1);
            k_fin_alpha<<<Bn, 256, 0, stream>>>(part, st, ncg, i);
            k_axpy<<<dim3(PB, Bn), 256, 0, stream>>>((float4*)xb, (float4*)rbuf, (float4*)pbuf,
                                                     (const float4*)qb, part, st, ncg, i);
            k_fin_iter<<<Bn, 256, 0, stream>>>(part, st, ncg, i, 1);
        }
    };

    // CG solve 1 (idx 0, zero reg targets, x0 = blurred)
    solve(0, nullptr, 0);

    // bilateral grid stage (stage 0), in-place on xb
    dim3 sb(8, 8), sg(GW, GH, Bn * Cn);
    k_splat<<<sg, sb, 0, stream>>>(xb, g0);
    const int totalg = Bn * Cn * GH * GW * NBn;
    k_blur<<<(totalg + 255) / 256, 256, 0, stream>>>(g0, g1, fs, 11, 0);
    k_blur<<<(totalg + 255) / 256, 256, 0, stream>>>(g1, g0, fs, 11, 1);
    k_blur<<<(totalg + 255) / 256, 256, 0, stream>>>(g0, g1, fr, 5, 2);
    k_slice<<<dim3(PLANE / 256, 1, Bn * Cn), 256, 0, stream>>>(xb, g1, xb);

    // shrinkage prior -> reg targets (reg_kernels[1], thresholds[0])
    k_prior<<<dim3(Ww / 16, Hh / 16, Bn * Cn), tb, 0, stream>>>(xb, tg, rks + NRK * 25, thr);

    // CG solve 2 (idx 1, with targets, x0 = bilateral output)
    solve(1, tg, 1);

    hipMemcpyAsync(d_out, xb, (size_t)Bn * CHW * sizeof(float),
                   hipMemcpyDeviceToDevice, stream);
}

// Round 3
// 1564.544 us; speedup vs baseline: 2.4156x; 1.1215x over previous
//
#include <hip/hip_runtime.h>

// ---------------- problem constants (match setup_inputs) ----------------
constexpr int Bn = 2, Cn = 3, Hh = 512, Ww = 512;
constexpr int KS = 15, KR = 7;          // PSF kernel
constexpr int NDK = 6, NRK = 5;         // data / reg bank sizes (5x5, r=2)
constexpr int GH = 64, GW = 64, NBn = 9, SS = 8;  // bilateral grid
constexpr float EPSf = 1e-8f;
constexpr float CGTOL = 1e-4f;
constexpr int PLANE = Hh * Ww;
constexpr int CHW = Cn * PLANE;
constexpr int BX = 64, BY = 16;         // conv output tile (4 px/thread in x)
constexpr int GXc = Ww / BX, GYc = Hh / BY;   // 8 x 32
constexpr int PB = GXc * GYc * Cn;      // 768 partial-blocks per batch
constexpr int SA = 80, THt = 30;        // 15x15 halo tile: 78x30 data, stride 80
constexpr int S2W = 72, S2H = 24;       // 5x5-bank src tile (halo 4): 72x24
constexpr int PHW = 68, PHH = 20;       // 5x5-bank mid tile (halo 2): 68x20
constexpr int PHG = (PHW / 4) * PHH;    // 340 float4-groups in mid tile
constexpr int NITER = 5;

struct CgState { float alpha, beta, rn, r0; int done, pflag; int pad0, pad1; };

__device__ __forceinline__ float blockReduce(float v, float* red, int tid) {
    red[tid] = v; __syncthreads();
    for (int s = 128; s > 0; s >>= 1) { if (tid < s) red[tid] += red[tid + s]; __syncthreads(); }
    float r = red[0]; __syncthreads();
    return r;
}

// ---------------------------------------------------------------------
// k_conv15: 15x15 correlation, 64x16 tile, 4 px/thread.
// mode 0: v = src, copy v -> xcopy (interior), out = corr(v) - sub
// mode 1: v = src,                          out = corr(v) - sub
// mode 2: v = p_cur = pflag ? r + beta*p : p ; out = corr(v);
//         num = sum_interior r*p_cur -> part slot0
// ---------------------------------------------------------------------
__global__ __launch_bounds__(256)
void k_conv15(const float* __restrict__ src, const float* __restrict__ rb,
              const float* __restrict__ pbuf, float* __restrict__ xcopy,
              const float* __restrict__ sub, float* __restrict__ out,
              const float* __restrict__ kernB, float* __restrict__ part,
              const CgState* __restrict__ st, const int* __restrict__ ncg,
              int iter, int mode)
{
    const int pz = blockIdx.z, b = pz / Cn, c = pz % Cn;
    const CgState s = st[b];
    if (mode == 2 && (s.done != 0 || iter >= *ncg)) return;
    __shared__ __align__(16) float tile[SA * THt];
    __shared__ __align__(16) float kkp[15 * 16];
    __shared__ float red[256];
    const int tx = threadIdx.x, ty = threadIdx.y, tid = ty * 16 + tx;
    const int ox0 = blockIdx.x * BX, oy0 = blockIdx.y * BY;
    const int baseP = pz * PLANE;
    const float beta = s.beta; const int pf = s.pflag;

    const float* kp = kernB + b * 225;
    for (int i = tid; i < 225; i += 256) kkp[(i / 15) * 16 + (i % 15)] = kp[i];

    float nm = 0.f;
    for (int i = tid; i < 78 * THt; i += 256) {
        int ly = i / 78, lx = i % 78;
        int gy = oy0 - KR + ly, gx = ox0 - KR + lx;
        float v = 0.f;
        if (gy >= 0 && gy < Hh && gx >= 0 && gx < Ww) {
            int gi = baseP + gy * Ww + gx;
            if (mode == 2) {
                float rv = rb[gi], pv = pbuf[gi];
                v = pf ? fmaf(beta, pv, rv) : pv;
                if (ly >= KR && ly < KR + BY && lx >= KR && lx < KR + BX)
                    nm = fmaf(rv, v, nm);
            } else {
                v = src[gi];
                if (mode == 0 && ly >= KR && ly < KR + BY && lx >= KR && lx < KR + BX)
                    xcopy[gi] = v;
            }
        }
        tile[ly * SA + lx] = v;
    }
    __syncthreads();

    const int colbase = tx * 4;
    float a0 = 0.f, a1 = 0.f, a2 = 0.f, a3 = 0.f;
    for (int i = 0; i < KS; i++) {
        const float4* rp4 = reinterpret_cast<const float4*>(&tile[(ty + i) * SA + colbase]);
        float f[20];
        #pragma unroll
        for (int s5 = 0; s5 < 5; s5++) {
            float4 w4 = rp4[s5];
            f[s5 * 4] = w4.x; f[s5 * 4 + 1] = w4.y; f[s5 * 4 + 2] = w4.z; f[s5 * 4 + 3] = w4.w;
        }
        const float4* kr4 = reinterpret_cast<const float4*>(&kkp[i * 16]);
        float kf[16];
        #pragma unroll
        for (int s5 = 0; s5 < 4; s5++) {
            float4 k4 = kr4[s5];
            kf[s5 * 4] = k4.x; kf[s5 * 4 + 1] = k4.y; kf[s5 * 4 + 2] = k4.z; kf[s5 * 4 + 3] = k4.w;
        }
        #pragma unroll
        for (int j = 0; j < KS; j++) {
            float kv = kf[j];
            a0 = fmaf(kv, f[j], a0); a1 = fmaf(kv, f[j + 1], a1);
            a2 = fmaf(kv, f[j + 2], a2); a3 = fmaf(kv, f[j + 3], a3);
        }
    }
    const int gi = baseP + (oy0 + ty) * Ww + ox0 + colbase;
    if (sub) {
        float4 sv = *reinterpret_cast<const float4*>(&sub[gi]);
        a0 -= sv.x; a1 -= sv.y; a2 -= sv.z; a3 -= sv.w;
    }
    *reinterpret_cast<float4*>(&out[gi]) = make_float4(a0, a1, a2, a3);
    if (mode == 2) {
        float tot = blockReduce(nm, red, tid);
        if (tid == 0) {
            int blk = c * (GXc * GYc) + blockIdx.y * GXc + blockIdx.x;
            part[((size_t)b * 4 + 0) * PB + blk] = tot;
        }
    }
}

// ---------------------------------------------------------------------
// k_bank: t = sum_n 2*dkw_n * bankT_n(bank_n(s))   (d zeroed outside image)
// Fast path: every active 5x5 is a single-nonzero (delta) kernel ->
//   t(y,x) = sum_n 2*dkw_n*v_n^2 * s(y,x) * [ (y-dy,x-dx) in image ]
// ---------------------------------------------------------------------
__global__ __launch_bounds__(256)
void k_bank(const float* __restrict__ sbuf, float* __restrict__ tbuf,
            const float* __restrict__ dks, const float* __restrict__ dkw,
            const CgState* __restrict__ st, const int* __restrict__ ncg,
            int iter, int mode)
{
    const int pz = blockIdx.z, b = pz / Cn;
    if (mode == 1 && (st[b].done != 0 || iter >= *ncg)) return;
    __shared__ __align__(16) float sl[S2W * S2H];
    __shared__ __align__(16) float dl[PHW * PHH];
    __shared__ float dkk[NDK * 25];
    __shared__ float dww[NDK];
    const int tx = threadIdx.x, ty = threadIdx.y, tid = ty * 16 + tx;
    const int ox0 = blockIdx.x * BX, oy0 = blockIdx.y * BY;
    const int baseP = pz * PLANE;
    const int colbase = tx * 4;
    for (int i = tid; i < NDK * 25; i += 256) dkk[i] = dks[i];
    if (tid < NDK) dww[tid] = dkw[tid];
    __syncthreads();

    // uniform delta detection (all threads compute identically from shared)
    bool fast = true;
    for (int n = 0; n < NDK; n++) {
        if (dww[n] == 0.f) continue;
        int nnz = 0;
        for (int q = 0; q < 25; q++) if (dkk[n * 25 + q] != 0.f) nnz++;
        if (nnz > 1) fast = false;
    }

    if (fast) {
        const int gy = oy0 + ty, gx0 = ox0 + colbase;
        const float4 sv = *reinterpret_cast<const float4*>(&sbuf[baseP + gy * Ww + gx0]);
        float o0 = 0.f, o1 = 0.f, o2 = 0.f, o3 = 0.f;
        for (int n = 0; n < NDK; n++) {
            float wn = 2.f * dww[n];
            if (wn == 0.f) continue;
            int pa = -1, pb = 0; float pv = 0.f;
            for (int q = 0; q < 25; q++) {
                float vq = dkk[n * 25 + q];
                if (vq != 0.f) { pa = q / 5; pb = q % 5; pv = vq; }
            }
            if (pa < 0) continue;                 // all-zero kernel
            int dy = pa - 2, dx = pb - 2;
            float sc = wn * pv * pv;
            if ((gy - dy) < 0 || (gy - dy) >= Hh) continue;
            if ((gx0     - dx) >= 0 && (gx0     - dx) < Ww) o0 = fmaf(sc, sv.x, o0);
            if ((gx0 + 1 - dx) >= 0 && (gx0 + 1 - dx) < Ww) o1 = fmaf(sc, sv.y, o1);
            if ((gx0 + 2 - dx) >= 0 && (gx0 + 2 - dx) < Ww) o2 = fmaf(sc, sv.z, o2);
            if ((gx0 + 3 - dx) >= 0 && (gx0 + 3 - dx) < Ww) o3 = fmaf(sc, sv.w, o3);
        }
        *reinterpret_cast<float4*>(&tbuf[baseP + gy * Ww + gx0]) = make_float4(o0, o1, o2, o3);
        return;
    }

    // ---- generic tiled path ----
    for (int i = tid; i < S2W * S2H; i += 256) {
        int ly = i / S2W, lx = i % S2W;
        int gy = oy0 - 4 + ly, gx = ox0 - 4 + lx;
        sl[i] = (gy >= 0 && gy < Hh && gx >= 0 && gx < Ww) ? sbuf[baseP + gy * Ww + gx] : 0.f;
    }
    __syncthreads();
    float t0 = 0.f, t1 = 0.f, t2 = 0.f, t3 = 0.f;
    for (int n = 0; n < NDK; n++) {
        float wn = 2.f * dww[n];
        if (wn == 0.f) continue;
        float dnr[25];
        #pragma unroll
        for (int q = 0; q < 25; q++) dnr[q] = dkk[n * 25 + q];
        for (int t = tid; t < PHG; t += 256) {
            int zy = t / 17, zx0 = (t % 17) * 4;
            int gy = oy0 - 2 + zy, gx0 = ox0 - 2 + zx0;
            float v0 = 0.f, v1 = 0.f, v2 = 0.f, v3 = 0.f;
            #pragma unroll
            for (int a = 0; a < 5; a++) {
                bool rz = dnr[a*5]==0.f && dnr[a*5+1]==0.f && dnr[a*5+2]==0.f &&
                          dnr[a*5+3]==0.f && dnr[a*5+4]==0.f;
                if (rz) continue;
                const float4* s4 = reinterpret_cast<const float4*>(&sl[(zy + a) * S2W + zx0]);
                float4 u0 = s4[0], u1 = s4[1];
                float f8[8] = {u0.x,u0.y,u0.z,u0.w,u1.x,u1.y,u1.z,u1.w};
                #pragma unroll
                for (int bb = 0; bb < 5; bb++) {
                    float kv = dnr[a * 5 + bb];
                    if (kv != 0.f) {
                        v0 = fmaf(kv, f8[bb], v0); v1 = fmaf(kv, f8[bb+1], v1);
                        v2 = fmaf(kv, f8[bb+2], v2); v3 = fmaf(kv, f8[bb+3], v3);
                    }
                }
            }
            bool gyin = (gy >= 0 && gy < Hh);
            if (!gyin || gx0     < 0 || gx0     >= Ww) v0 = 0.f;
            if (!gyin || gx0 + 1 < 0 || gx0 + 1 >= Ww) v1 = 0.f;
            if (!gyin || gx0 + 2 < 0 || gx0 + 2 >= Ww) v2 = 0.f;
            if (!gyin || gx0 + 3 < 0 || gx0 + 3 >= Ww) v3 = 0.f;
            *reinterpret_cast<float4*>(&dl[zy * PHW + zx0]) = make_float4(v0, v1, v2, v3);
        }
        __syncthreads();
        float c0 = 0.f, c1 = 0.f, c2 = 0.f, c3 = 0.f;
        #pragma unroll
        for (int a = 0; a < 5; a++) {
            int fr = 4 - a;
            bool rz = dnr[fr*5]==0.f && dnr[fr*5+1]==0.f && dnr[fr*5+2]==0.f &&
                      dnr[fr*5+3]==0.f && dnr[fr*5+4]==0.f;
            if (rz) continue;
            const float4* q4 = reinterpret_cast<const float4*>(&dl[(ty + a) * PHW + colbase]);
            float4 u0 = q4[0], u1 = q4[1];
            float f8[8] = {u0.x,u0.y,u0.z,u0.w,u1.x,u1.y,u1.z,u1.w};
            #pragma unroll
            for (int bb = 0; bb < 5; bb++) {
                float kv = dnr[fr * 5 + (4 - bb)];
                if (kv != 0.f) {
                    c0 = fmaf(kv, f8[bb], c0); c1 = fmaf(kv, f8[bb+1], c1);
                    c2 = fmaf(kv, f8[bb+2], c2); c3 = fmaf(kv, f8[bb+3], c3);
                }
            }
        }
        t0 = fmaf(wn, c0, t0); t1 = fmaf(wn, c1, t1);
        t2 = fmaf(wn, c2, t2); t3 = fmaf(wn, c3, t3);
        __syncthreads();
    }
    const int gi = baseP + (oy0 + ty) * Ww + ox0 + colbase;
    *reinterpret_cast<float4*>(&tbuf[gi]) = make_float4(t0, t1, t2, t3);
}

// ---------------------------------------------------------------------
// k_grad:
// mode 0 (GRAD): g = corr15T(wbuf) + sum_m bankT(rkw*rp*sign(v)(|v|+EPS)^(rp-1)),
//                v = bank_m(x) - tgt_m ;  write r=-g, p=r ; slot2 = ||r||^2
// mode 1 (HESS): q = corr15T(wbuf) + sum_m bankT(rkw*rp*(rp-1)*fac*bank_m(p_cur)),
//                p_cur = pflag ? r+beta*p : p ; write q ; slot1 = sum p_cur*q
// ---------------------------------------------------------------------
__global__ __launch_bounds__(256)
void k_grad(const float* __restrict__ wbuf, const float* __restrict__ xg,
            const float* __restrict__ rb, const float* __restrict__ pbuf,
            const float* __restrict__ tgt, float* __restrict__ outb,
            float* __restrict__ pout, const float* __restrict__ kernB,
            const float* __restrict__ rks, const float* __restrict__ rkw,
            const float* __restrict__ rpw, float* __restrict__ part,
            const CgState* __restrict__ st, const int* __restrict__ ncg,
            int iter, int mode)
{
    const int pz = blockIdx.z, b = pz / Cn, c = pz % Cn;
    const CgState s = st[b];
    if (mode == 1 && (s.done != 0 || iter >= *ncg)) return;
    __shared__ __align__(16) float wt[SA * THt];
    __shared__ __align__(16) float s2[S2W * S2H];
    __shared__ __align__(16) float ph[PHW * PHH];
    __shared__ __align__(16) float kkp[15 * 16];     // flipped PSF
    __shared__ float rk5[NRK * 25];
    __shared__ float srkw[NRK], srpw[NRK];
    __shared__ float red[256];
    const int tx = threadIdx.x, ty = threadIdx.y, tid = ty * 16 + tx;
    const int ox0 = blockIdx.x * BX, oy0 = blockIdx.y * BY;
    const int baseP = pz * PLANE;
    const float beta = s.beta; const int pf = s.pflag;

    const float* kp = kernB + b * 225;
    for (int i = tid; i < 225; i += 256) kkp[(i / 15) * 16 + (i % 15)] = kp[224 - i];
    for (int i = tid; i < NRK * 25; i += 256) rk5[i] = rks[i];
    if (tid < NRK) { srkw[tid] = rkw[tid]; srpw[tid] = rpw[tid]; }

    for (int i = tid; i < 78 * THt; i += 256) {
        int ly = i / 78, lx = i % 78;
        int gy = oy0 - KR + ly, gx = ox0 - KR + lx;
        wt[ly * SA + lx] = (gy >= 0 && gy < Hh && gx >= 0 && gx < Ww)
                           ? wbuf[baseP + gy * Ww + gx] : 0.f;
    }
    for (int i = tid; i < S2W * S2H; i += 256) {
        int ly = i / S2W, lx = i % S2W;
        int gy = oy0 - 4 + ly, gx = ox0 - 4 + lx;
        float v = 0.f;
        if (gy >= 0 && gy < Hh && gx >= 0 && gx < Ww) {
            int gi = baseP + gy * Ww + gx;
            if (mode == 0) v = xg[gi];
            else { float rv = rb[gi], pv = pbuf[gi]; v = pf ? fmaf(beta, pv, rv) : pv; }
        }
        s2[i] = v;
    }
    __syncthreads();

    const int colbase = tx * 4;
    float a0 = 0.f, a1 = 0.f, a2 = 0.f, a3 = 0.f;
    for (int i = 0; i < KS; i++) {
        const float4* rp4 = reinterpret_cast<const float4*>(&wt[(ty + i) * SA + colbase]);
        float f[20];
        #pragma unroll
        for (int s5 = 0; s5 < 5; s5++) {
            float4 w4 = rp4[s5];
            f[s5 * 4] = w4.x; f[s5 * 4 + 1] = w4.y; f[s5 * 4 + 2] = w4.z; f[s5 * 4 + 3] = w4.w;
        }
        const float4* kr4 = reinterpret_cast<const float4*>(&kkp[i * 16]);
        float kf[16];
        #pragma unroll
        for (int s5 = 0; s5 < 4; s5++) {
            float4 k4 = kr4[s5];
            kf[s5 * 4] = k4.x; kf[s5 * 4 + 1] = k4.y; kf[s5 * 4 + 2] = k4.z; kf[s5 * 4 + 3] = k4.w;
        }
        #pragma unroll
        for (int j = 0; j < KS; j++) {
            float kv = kf[j];
            a0 = fmaf(kv, f[j], a0); a1 = fmaf(kv, f[j + 1], a1);
            a2 = fmaf(kv, f[j + 2], a2); a3 = fmaf(kv, f[j + 3], a3);
        }
    }

    for (int m = 0; m < NRK; m++) {
        float wm = srkw[m], rp = srpw[m];
        if (wm == 0.f) continue;  // uniform
        float rmr[25];
        #pragma unroll
        for (int q = 0; q < 25; q++) rmr[q] = rk5[m * 25 + q];
        const float* tgm = tgt ? tgt + ((size_t)(b * NRK + m)) * CHW + (size_t)c * PLANE : nullptr;
        const float coefG = wm * rp;
        const float coefH = wm * rp * (rp - 1.f);

        for (int t = tid; t < PHG; t += 256) {
            int zy = t / 17, zx0 = (t % 17) * 4;
            int gy = oy0 - 2 + zy, gx0 = ox0 - 2 + zx0;
            float v0 = 0.f, v1 = 0.f, v2 = 0.f, v3 = 0.f;
            #pragma unroll
            for (int a = 0; a < 5; a++) {
                bool rz = rmr[a*5]==0.f && rmr[a*5+1]==0.f && rmr[a*5+2]==0.f &&
                          rmr[a*5+3]==0.f && rmr[a*5+4]==0.f;
                if (rz) continue;
                const float4* s4 = reinterpret_cast<const float4*>(&s2[(zy + a) * S2W + zx0]);
                float4 u0 = s4[0], u1 = s4[1];
                float f8[8] = {u0.x,u0.y,u0.z,u0.w,u1.x,u1.y,u1.z,u1.w};
                #pragma unroll
                for (int bb = 0; bb < 5; bb++) {
                    float kv = rmr[a * 5 + bb];
                    if (kv != 0.f) {
                        v0 = fmaf(kv, f8[bb], v0); v1 = fmaf(kv, f8[bb+1], v1);
                        v2 = fmaf(kv, f8[bb+2], v2); v3 = fmaf(kv, f8[bb+3], v3);
                    }
                }
            }
            bool gyin = (gy >= 0 && gy < Hh);
            float o0 = 0.f, o1 = 0.f, o2 = 0.f, o3 = 0.f;
            if (mode == 0) {
                if (gyin && gx0     >= 0 && gx0     < Ww) {
                    float v = v0; if (tgm) v -= tgm[gy * Ww + gx0];
                    float sg = (v > 0.f) ? 1.f : ((v < 0.f) ? -1.f : 0.f);
                    float av = fabsf(v) + EPSf;
                    o0 = coefG * sg * ((rp == 2.f) ? av : powf(av, rp - 1.f));
                }
                if (gyin && gx0 + 1 >= 0 && gx0 + 1 < Ww) {
                    float v = v1; if (tgm) v -= tgm[gy * Ww + gx0 + 1];
                    float sg = (v > 0.f) ? 1.f : ((v < 0.f) ? -1.f : 0.f);
                    float av = fabsf(v) + EPSf;
                    o1 = coefG * sg * ((rp == 2.f) ? av : powf(av, rp - 1.f));
                }
                if (gyin && gx0 + 2 >= 0 && gx0 + 2 < Ww) {
                    float v = v2; if (tgm) v -= tgm[gy * Ww + gx0 + 2];
                    float sg = (v > 0.f) ? 1.f : ((v < 0.f) ? -1.f : 0.f);
                    float av = fabsf(v) + EPSf;
                    o2 = coefG * sg * ((rp == 2.f) ? av : powf(av, rp - 1.f));
                }
                if (gyin && gx0 + 3 >= 0 && gx0 + 3 < Ww) {
                    float v = v3; if (tgm) v -= tgm[gy * Ww + gx0 + 3];
                    float sg = (v > 0.f) ? 1.f : ((v < 0.f) ? -1.f : 0.f);
                    float av = fabsf(v) + EPSf;
                    o3 = coefG * sg * ((rp == 2.f) ? av : powf(av, rp - 1.f));
                }
            } else {
                // fac = (|bank_m(x)-t|+EPS)^(rp-2); == 1 when rp==2 (hot path)
                #pragma unroll
                for (int j = 0; j < 4; j++) {
                    int gx = gx0 + j;
                    if (!gyin || gx < 0 || gx >= Ww) continue;
                    float v = (j == 0) ? v0 : (j == 1) ? v1 : (j == 2) ? v2 : v3;
                    float fac = 1.f;
                    if (rp != 2.f) {
                        float vx = 0.f;
                        for (int a = 0; a < 5; a++)
                            for (int bb = 0; bb < 5; bb++) {
                                int yy = gy - 2 + a, xx = gx - 2 + bb;
                                if (yy >= 0 && yy < Hh && xx >= 0 && xx < Ww)
                                    vx = fmaf(rmr[a * 5 + bb], xg[baseP + yy * Ww + xx], vx);
                            }
                        if (tgm) vx -= tgm[gy * Ww + gx];
                        fac = powf(fabsf(vx) + EPSf, rp - 2.f);
                    }
                    float o = coefH * fac * v;
                    if (j == 0) o0 = o; else if (j == 1) o1 = o; else if (j == 2) o2 = o; else o3 = o;
                }
            }
            *reinterpret_cast<float4*>(&ph[zy * PHW + zx0]) = make_float4(o0, o1, o2, o3);
        }
        __syncthreads();
        #pragma unroll
        for (int a = 0; a < 5; a++) {
            int fr = 4 - a;
            bool rz = rmr[fr*5]==0.f && rmr[fr*5+1]==0.f && rmr[fr*5+2]==0.f &&
                      rmr[fr*5+3]==0.f && rmr[fr*5+4]==0.f;
            if (rz) continue;
            const float4* q4 = reinterpret_cast<const float4*>(&ph[(ty + a) * PHW + colbase]);
            float4 u0 = q4[0], u1 = q4[1];
            float f8[8] = {u0.x,u0.y,u0.z,u0.w,u1.x,u1.y,u1.z,u1.w};
            #pragma unroll
            for (int bb = 0; bb < 5; bb++) {
                float kv = rmr[fr * 5 + (4 - bb)];
                if (kv != 0.f) {
                    a0 = fmaf(kv, f8[bb], a0); a1 = fmaf(kv, f8[bb+1], a1);
                    a2 = fmaf(kv, f8[bb+2], a2); a3 = fmaf(kv, f8[bb+3], a3);
                }
            }
        }
        __syncthreads();
    }

    const int gi = baseP + (oy0 + ty) * Ww + ox0 + colbase;
    float redv;
    if (mode == 0) {
        float r0v = -a0, r1v = -a1, r2v = -a2, r3v = -a3;
        float4 rv4 = make_float4(r0v, r1v, r2v, r3v);
        *reinterpret_cast<float4*>(&outb[gi]) = rv4;
        *reinterpret_cast<float4*>(&pout[gi]) = rv4;
        redv = r0v * r0v + r1v * r1v + r2v * r2v + r3v * r3v;
    } else {
        *reinterpret_cast<float4*>(&outb[gi]) = make_float4(a0, a1, a2, a3);
        int li = (ty + 4) * S2W + colbase + 4;
        redv = s2[li] * a0 + s2[li + 1] * a1 + s2[li + 2] * a2 + s2[li + 3] * a3;
    }
    float tot = blockReduce(redv, red, tid);
    if (tid == 0) {
        int blk = c * (GXc * GYc) + blockIdx.y * GXc + blockIdx.x;
        int slot = (mode == 0) ? 2 : 1;
        part[((size_t)b * 4 + slot) * PB + blk] = tot;
    }
}

// ---------------------------------------------------------------------
// k_axpy: p_cur = pflag ? r+beta*p : p ; x += alpha*p_cur ; r -= alpha*q ;
//         persist p = p_cur ; slot2 = ||r_new||^2
// ---------------------------------------------------------------------
__global__ __launch_bounds__(256)
void k_axpy(float4* __restrict__ x, float4* __restrict__ r, float4* __restrict__ p,
            const float4* __restrict__ q, float* __restrict__ part,
            const CgState* __restrict__ st, const int* __restrict__ ncg, int iter)
{
    const int b = blockIdx.y;
    const CgState s = st[b];
    if (s.done != 0 || iter >= *ncg) return;
    __shared__ float red[256];
    const int tid = threadIdx.x;
    const int idx = b * (CHW / 4) + blockIdx.x * 256 + tid;
    float4 pv = p[idx], rv = r[idx], qv = q[idx], xv = x[idx];
    float4 pc;
    if (s.pflag) {
        pc.x = fmaf(s.beta, pv.x, rv.x); pc.y = fmaf(s.beta, pv.y, rv.y);
        pc.z = fmaf(s.beta, pv.z, rv.z); pc.w = fmaf(s.beta, pv.w, rv.w);
    } else pc = pv;
    xv.x = fmaf(s.alpha, pc.x, xv.x); xv.y = fmaf(s.alpha, pc.y, xv.y);
    xv.z = fmaf(s.alpha, pc.z, xv.z); xv.w = fmaf(s.alpha, pc.w, xv.w);
    rv.x = fmaf(-s.alpha, qv.x, rv.x); rv.y = fmaf(-s.alpha, qv.y, rv.y);
    rv.z = fmaf(-s.alpha, qv.z, rv.z); rv.w = fmaf(-s.alpha, qv.w, rv.w);
    x[idx] = xv; r[idx] = rv; p[idx] = pc;
    float nr = rv.x * rv.x + rv.y * rv.y + rv.z * rv.z + rv.w * rv.w;
    float tot = blockReduce(nr, red, tid);
    if (tid == 0) part[((size_t)b * 4 + 2) * PB + blockIdx.x] = tot;
}

__global__ __launch_bounds__(256)
void k_fin_alpha(const float* __restrict__ part, CgState* st,
                 const int* __restrict__ ncg, int iter)
{
    const int b = blockIdx.x, tid = threadIdx.x;
    __shared__ float red[256];
    if (st[b].done != 0 || iter >= *ncg) { if (tid == 0) st[b].alpha = 0.f; return; }
    float sn = 0.f, sd = 0.f;
    for (int i = tid; i < PB; i += 256) {
        sn += part[((size_t)b * 4 + 0) * PB + i];
        sd += part[((size_t)b * 4 + 1) * PB + i];
    }
    float num = blockReduce(sn, red, tid);
    float den = blockReduce(sd, red, tid);
    if (tid == 0) st[b].alpha = num / (den + 1e-12f);
}

__global__ __launch_bounds__(256)
void k_fin_iter(const float* __restrict__ part, CgState* st,
                const int* __restrict__ ncg, int iter, int mode)
{
    const int b = blockIdx.x, tid = threadIdx.x;
    __shared__ float red[256];
    if (mode == 1 && (st[b].done != 0 || iter >= *ncg)) { if (tid == 0) st[b].pflag = 0; return; }
    float s = 0.f;
    for (int i = tid; i < PB; i += 256) s += part[((size_t)b * 4 + 2) * PB + i];
    float nrn = blockReduce(s, red, tid);
    if (tid == 0) {
        if (mode == 0) {
            st[b].rn = nrn; st[b].r0 = nrn; st[b].done = 0; st[b].pflag = 0;
            st[b].beta = 0.f; st[b].alpha = 0.f;
        } else {
            float beta = nrn / (st[b].rn + 1e-20f);
            int conv = (nrn < CGTOL * st[b].r0) ? 1 : 0;
            st[b].beta = beta; st[b].rn = nrn;
            st[b].pflag = conv ? 0 : 1;
            if (conv) st[b].done = 1;
        }
    }
}

// ------------------------- bilateral grid -------------------------
__global__ __launch_bounds__(64)
void k_splat(const float* __restrict__ x, float* __restrict__ grid)
{
    __shared__ float bins[NBn * 2];
    const int tid = threadIdx.y * 8 + threadIdx.x;
    if (tid < NBn * 2) bins[tid] = 0.f;
    __syncthreads();
    const int pz = blockIdx.z;
    const int gy = blockIdx.y, gx = blockIdx.x;
    const int py = gy * 8 + threadIdx.y, px = gx * 8 + threadIdx.x;
    float I = x[(size_t)pz * PLANE + py * Ww + px];
    float Ic = fminf(fmaxf(I, 0.f), 1.f);
    int zi = (int)rintf(Ic * (NBn - 1));
    zi = min(max(zi, 0), NBn - 1);
    atomicAdd(&bins[zi * 2], Ic);
    atomicAdd(&bins[zi * 2 + 1], 1.f);
    __syncthreads();
    if (tid < NBn * 2)
        grid[(size_t)pz * GH * GW * NBn * 2 + ((size_t)gy * GW + gx) * NBn * 2 + tid] = bins[tid];
}

__global__ __launch_bounds__(256)
void k_blur(const float* __restrict__ in, float* __restrict__ out,
            const float* __restrict__ taps, int ntaps, int axis)
{
    const int id = blockIdx.x * 256 + threadIdx.x;
    const int total = Bn * Cn * GH * GW * NBn;
    if (id >= total) return;
    const int z = id % NBn;
    const int x = (id / NBn) % GW;
    const int y = (id / (NBn * GW)) % GH;
    const int p = id / (NBn * GW * GH);
    int coord, lim; long stride;
    if (axis == 0)      { coord = y; lim = GH;  stride = (long)GW * NBn * 2; }
    else if (axis == 1) { coord = x; lim = GW;  stride = NBn * 2; }
    else                { coord = z; lim = NBn; stride = 2; }
    const long base = (((long)(p * GH + y) * GW + x) * NBn + z) * 2;
    const int r = ntaps / 2;
    float a0 = 0.f, a1 = 0.f;
    for (int t = 0; t < ntaps; t++) {
        int cc = coord + t - r;
        if (cc < 0 || cc >= lim) continue;
        float w = taps[t];
        long ofs = base + (long)(cc - coord) * stride;
        a0 = fmaf(w, in[ofs], a0);
        a1 = fmaf(w, in[ofs + 1], a1);
    }
    out[base] = a0; out[base + 1] = a1;
}

__global__ __launch_bounds__(256)
void k_slice(const float* __restrict__ xin, const float* __restrict__ grid,
             float* __restrict__ xout)
{
    const int pz = blockIdx.z;
    const int id = blockIdx.x * 256 + threadIdx.x;
    const int py = id / Ww, px = id % Ww;
    float I = xin[(size_t)pz * PLANE + id];
    float Ic = fminf(fmaxf(I, 0.f), 1.f);
    float yf = (float)py / SS, xf = (float)px / SS, zf = Ic * (NBn - 1);
    int y0 = min(max((int)floorf(yf), 0), GH - 1); int y1 = min(y0 + 1, GH - 1);
    float wy = fminf(fmaxf(yf - (float)y0, 0.f), 1.f);
    int x0 = min(max((int)floorf(xf), 0), GW - 1); int x1 = min(x0 + 1, GW - 1);
    float wx = fminf(fmaxf(xf - (float)x0, 0.f), 1.f);
    int z0 = min(max((int)floorf(zf), 0), NBn - 1); int z1 = min(z0 + 1, NBn - 1);
    float wz = fminf(fmaxf(zf - (float)z0, 0.f), 1.f);
    const float* gp = grid + (size_t)pz * GH * GW * NBn * 2;
    const int   ys[2] = { y0, y1 };  const float wys[2] = { 1.f - wy, wy };
    const int   xs[2] = { x0, x1 };  const float wxs[2] = { 1.f - wx, wx };
    const int   zs[2] = { z0, z1 };  const float wzs[2] = { 1.f - wz, wz };
    float a0 = 0.f, a1 = 0.f;
    for (int iy = 0; iy < 2; iy++)
        for (int ix = 0; ix < 2; ix++)
            for (int iz = 0; iz < 2; iz++) {
                float w = wys[iy] * wxs[ix] * wzs[iz];
                size_t idx = (((size_t)ys[iy] * GW + xs[ix]) * NBn + zs[iz]) * 2;
                a0 = fmaf(w, gp[idx], a0);
                a1 = fmaf(w, gp[idx + 1], a1);
            }
    xout[(size_t)pz * PLANE + id] = a0 / (a1 + 1e-8f);
}

__global__ __launch_bounds__(256)
void k_prior(const float* __restrict__ x, float* __restrict__ tgt,
             const float* __restrict__ rks, const float* __restrict__ thr)
{
    const int pz = blockIdx.z, b = pz / Cn, c = pz % Cn;
    __shared__ float xl[24 * 24];
    __shared__ float rkk[NRK * 25];
    __shared__ float sthr[NRK];
    const int tx = threadIdx.x, ty = threadIdx.y, tid = ty * 16 + tx;
    const int ox0 = blockIdx.x * 16, oy0 = blockIdx.y * 16;
    const int baseP = pz * PLANE;
    for (int i = tid; i < NRK * 25; i += 256) rkk[i] = rks[i];
    if (tid < NRK) sthr[tid] = thr[tid];
    for (int i = tid; i < 24 * 24; i += 256) {
        int ly = i / 24, lx = i % 24;
        int gy = oy0 - 2 + ly, gx = ox0 - 2 + lx;
        xl[i] = (gy >= 0 && gy < Hh && gx >= 0 && gx < Ww) ? x[baseP + gy * Ww + gx] : 0.f;
    }
    __syncthreads();
    const int pix = (oy0 + ty) * Ww + (ox0 + tx);
    for (int m = 0; m < NRK; m++) {
        const float* rm = &rkk[m * 25];
        float v = 0.f;
        #pragma unroll
        for (int a = 0; a < 5; a++)
            #pragma unroll
            for (int bb = 0; bb < 5; bb++)
                v = fmaf(rm[a * 5 + bb], xl[(ty + a) * 24 + (tx + bb)], v);
        float sg = (v > 0.f) ? 1.f : ((v < 0.f) ? -1.f : 0.f);
        tgt[((size_t)(b * NRK + m)) * CHW + (size_t)c * PLANE + pix] =
            sg * fmaxf(fabsf(v) - sthr[m], 0.f);
    }
}

// ------------------------------ host ------------------------------
extern "C" void kernel_launch(void* const* d_in, const int* in_sizes, int n_in,
                              void* d_out, int out_size, void* d_ws, size_t ws_size,
                              hipStream_t stream)
{
    const float* blurred = (const float*)d_in[0];
    const float* kern    = (const float*)d_in[1];
    const float* dks     = (const float*)d_in[2];
    const float* dkw     = (const float*)d_in[3];
    const float* rks     = (const float*)d_in[4];
    const float* rkw     = (const float*)d_in[5];
    const float* rpw     = (const float*)d_in[6];
    const float* fs      = (const float*)d_in[7];
    const float* fr      = (const float*)d_in[8];
    const float* thr     = (const float*)d_in[9];
    const int*   ncg     = (const int*)d_in[10];
    (void)in_sizes; (void)n_in; (void)out_size; (void)ws_size;

    float* w = (float*)d_ws;
    size_t off = 0;
    auto alloc = [&](size_t n) { float* p = w + off; off += n; return p; };
    float* xb   = alloc((size_t)Bn * CHW);
    float* pbuf = alloc((size_t)Bn * CHW);
    float* rbuf = alloc((size_t)Bn * CHW);
    float* kx   = alloc((size_t)Bn * CHW);
    float* wb   = alloc((size_t)Bn * CHW);
    float* qb   = alloc((size_t)Bn * CHW);
    float* tg   = alloc((size_t)Bn * NRK * CHW);
    float* g0   = alloc((size_t)Bn * Cn * GH * GW * NBn * 2);
    float* g1   = alloc((size_t)Bn * Cn * GH * GW * NBn * 2);
    float* part = alloc((size_t)Bn * 4 * PB);
    CgState* st = (CgState*)(w + off); off += Bn * 8;

    dim3 tb(16, 16), grd(GXc, GYc, Bn * Cn);

    auto solve = [&](int idx, const float* tgt, int initmode) {
        const float* dks_i = dks + (size_t)idx * NDK * 25;
        const float* dkw_i = dkw + (size_t)idx * NDK;
        const float* rks_i = rks + (size_t)idx * NRK * 25;
        const float* rkw_i = rkw + (size_t)idx * NRK;
        const float* rpw_i = rpw + (size_t)idx * NRK;
        // init: Kx-b -> bank -> gradient (r = p = -g, r0 = ||r||^2)
        k_conv15<<<grd, tb, 0, stream>>>(initmode == 0 ? blurred : xb, nullptr, nullptr,
                                         initmode == 0 ? xb : nullptr, blurred, kx, kern,
                                         nullptr, st, ncg, 0, initmode == 0 ? 0 : 1);
        k_bank<<<grd, tb, 0, stream>>>(kx, wb, dks_i, dkw_i, st, ncg, 0, 0);
        k_grad<<<grd, tb, 0, stream>>>(wb, xb, nullptr, nullptr, tgt, rbuf, pbuf, kern,
                                       rks_i, rkw_i, rpw_i, part, st, ncg, 0, 0);
        k_fin_iter<<<Bn, 256, 0, stream>>>(part, st, ncg, 0, 0);
        for (int i = 0; i < NITER; i++) {
            // q = A * p_cur ; num = r.p_cur ; den = p_cur.q
            k_conv15<<<grd, tb, 0, stream>>>(nullptr, rbuf, pbuf, nullptr, nullptr, kx, kern,
                                             part, st, ncg, i, 2);
            k_bank<<<grd, tb, 0, stream>>>(kx, wb, dks_i, dkw_i, st, ncg, i, 1);
            k_grad<<<grd, tb, 0, stream>>>(wb, xb, rbuf, pbuf, tgt, qb, nullptr, kern,
                                           rks_i, rkw_i, rpw_i, part, st, ncg, i, 1);
            k_fin_alpha<<<Bn, 256, 0, stream>>>(part, st, ncg, i);
            k_axpy<<<dim3(PB, Bn), 256, 0, stream>>>((float4*)xb, (float4*)rbuf, (float4*)pbuf,
                                                     (const float4*)qb, part, st, ncg, i);
            k_fin_iter<<<Bn, 256, 0, stream>>>(part, st, ncg, i, 1);
        }
    };

    // CG solve 1 (idx 0, zero reg targets, x0 = blurred)
    solve(0, nullptr, 0);

    // bilateral grid stage (stage 0), in-place on xb
    dim3 sb(8, 8), sg(GW, GH, Bn * Cn);
    k_splat<<<sg, sb, 0, stream>>>(xb, g0);
    const int totalg = Bn * Cn * GH * GW * NBn;
    k_blur<<<(totalg + 255) / 256, 256, 0, stream>>>(g0, g1, fs, 11, 0);
    k_blur<<<(totalg + 255) / 256, 256, 0, stream>>>(g1, g0, fs, 11, 1);
    k_blur<<<(totalg + 255) / 256, 256, 0, stream>>>(g0, g1, fr, 5, 2);
    k_slice<<<dim3(PLANE / 256, 1, Bn * Cn), 256, 0, stream>>>(xb, g1, xb);

    // shrinkage prior -> reg targets (reg_kernels[1], thresholds[0])
    k_prior<<<dim3(Ww / 16, Hh / 16, Bn * Cn), tb, 0, stream>>>(xb, tg, rks + NRK * 25, thr);

    // CG solve 2 (idx 1, with targets, x0 = bilateral output)
    solve(1, tg, 1);

    hipMemcpyAsync(d_out, xb, (size_t)Bn * CHW * sizeof(float),
                   hipMemcpyDeviceToDevice, stream);
}